// Round 2
// baseline (970.026 us; speedup 1.0000x reference)
//
#include <hip/hip_runtime.h>
#include <stdint.h>

// Problem dims (fixed by the reference)
#define TT 256
#define SS 256
#define FF 1024
#define AA 256

typedef __attribute__((ext_vector_type(8))) short short8;
typedef __attribute__((ext_vector_type(8))) unsigned short ushort8v;
typedef __attribute__((ext_vector_type(4))) float floatx4;

// fp32 -> bf16 round-to-nearest-even
__device__ __forceinline__ unsigned short f2bf(float f) {
  unsigned int u = __float_as_uint(f);
  u += 0x7FFFu + ((u >> 16) & 1u);
  return (unsigned short)(u >> 16);
}

// async global->LDS, 16 B per lane; LDS dest = wave-uniform base + lane*16
__device__ __forceinline__ void gl_lds16(const unsigned short* g, unsigned short* l) {
  __builtin_amdgcn_global_load_lds(
      (__attribute__((address_space(1))) void*)(g),
      (__attribute__((address_space(3))) void*)(l), 16, 0, 0);
}

// ---------------------------------------------------------------------------
// Whole-tensor fp32 -> bf16 convert (memory-bound pre-pass for batch).
// ---------------------------------------------------------------------------
__global__ __launch_bounds__(256) void k_cvt_bf16(const float* __restrict__ in,
                                                  unsigned short* __restrict__ out,
                                                  long n8) {
  long i = (long)blockIdx.x * 256 + threadIdx.x;
  const long stride = (long)gridDim.x * 256;
  for (; i < n8; i += stride) {
    const floatx4 v0 = *(const floatx4*)(in + i * 8);
    const floatx4 v1 = *(const floatx4*)(in + i * 8 + 4);
    ushort8v h;
    h[0] = f2bf(v0.x); h[1] = f2bf(v0.y); h[2] = f2bf(v0.z); h[3] = f2bf(v0.w);
    h[4] = f2bf(v1.x); h[5] = f2bf(v1.y); h[6] = f2bf(v1.z); h[7] = f2bf(v1.w);
    *(ushort8v*)(out + i * 8) = h;
  }
}

// ---------------------------------------------------------------------------
// Weight transpose + fp32->bf16:  WT[n][k] = bf16(W[k][n]).  W: K x N fp32.
// ---------------------------------------------------------------------------
__global__ void k_transpose_cvt(const float* __restrict__ W,
                                unsigned short* __restrict__ WT,
                                int K, int N) {
  __shared__ float tile[32][33];
  const int bk = blockIdx.x * 32, bn = blockIdx.y * 32;
  const int tx = threadIdx.x, ty = threadIdx.y;
  for (int i = ty; i < 32; i += 8)
    tile[i][tx] = W[(size_t)(bk + i) * N + bn + tx];
  __syncthreads();
  for (int i = ty; i < 32; i += 8)
    WT[(size_t)(bn + i) * K + bk + tx] = f2bf(tile[tx][i]);
}

// ---------------------------------------------------------------------------
// Fused projection GEMM, bf16-A (m97 structure, both operands via
// global_load_lds width-16):
//   C = batch16(65536x1024 bf16) @ [aT|bT|gT]^T + bias
//   n-tile 0..1 -> theta ; 2..3 -> phi ; 4..11 -> featsT[t][f][s]
// ---------------------------------------------------------------------------
__global__ __launch_bounds__(256) void k_proj_b16(
    const unsigned short* __restrict__ batch16,
    const unsigned short* __restrict__ aT,
    const unsigned short* __restrict__ bT,
    const unsigned short* __restrict__ gT,
    const float* __restrict__ a_b, const float* __restrict__ b_b,
    const float* __restrict__ g_b,
    unsigned short* __restrict__ theta,
    unsigned short* __restrict__ phi,
    unsigned short* __restrict__ featsT) {
  const int K = FF;  // 1024
  __shared__ unsigned short As[128 * 32];
  __shared__ unsigned short Bs[128 * 32];

  const int nt = blockIdx.x, mt = blockIdx.y;
  const int m0 = mt * 128;
  const unsigned short* Wt;
  const float* bias;
  int nloc0, mode;  // mode: 0 theta, 1 phi, 2 featsT
  if (nt < 2)      { Wt = aT; bias = a_b; nloc0 = nt * 128;       mode = 0; }
  else if (nt < 4) { Wt = bT; bias = b_b; nloc0 = (nt - 2) * 128; mode = 1; }
  else             { Wt = gT; bias = g_b; nloc0 = (nt - 4) * 128; mode = 2; }

  const int tid = threadIdx.x;
  const int lane = tid & 63, wave = tid >> 6;
  const int wm = wave >> 1, wn = wave & 1;
  const int lr = lane & 15, lq = lane >> 4;

  floatx4 acc[4][4];
#pragma unroll
  for (int i = 0; i < 4; i++)
#pragma unroll
    for (int j = 0; j < 4; j++) acc[i][j] = (floatx4)0.0f;

  for (int k0 = 0; k0 < K; k0 += 32) {
    __syncthreads();
    int sl = tid;
    gl_lds16(batch16 + (size_t)(m0 + (sl >> 2)) * K + k0 + (sl & 3) * 8,
             &As[wave * 512]);
    gl_lds16(Wt + (size_t)(nloc0 + (sl >> 2)) * K + k0 + (sl & 3) * 8,
             &Bs[wave * 512]);
    sl = tid + 256;
    gl_lds16(batch16 + (size_t)(m0 + (sl >> 2)) * K + k0 + (sl & 3) * 8,
             &As[2048 + wave * 512]);
    gl_lds16(Wt + (size_t)(nloc0 + (sl >> 2)) * K + k0 + (sl & 3) * 8,
             &Bs[2048 + wave * 512]);
    __syncthreads();

    short8 af[4], bfr[4];
#pragma unroll
    for (int i = 0; i < 4; i++)
      af[i] = *(const short8*)&As[(wm * 64 + i * 16 + lr) * 32 + lq * 8];
#pragma unroll
    for (int j = 0; j < 4; j++)
      bfr[j] = *(const short8*)&Bs[(wn * 64 + j * 16 + lr) * 32 + lq * 8];
#pragma unroll
    for (int i = 0; i < 4; i++)
#pragma unroll
      for (int j = 0; j < 4; j++)
        acc[i][j] = __builtin_amdgcn_mfma_f32_16x16x32_bf16(af[i], bfr[j],
                                                            acc[i][j], 0, 0, 0);
  }

  // Epilogue. C/D layout: col = lane&15, row = (lane>>4)*4 + reg.
#pragma unroll
  for (int i = 0; i < 4; i++) {
    const int row0 = wm * 64 + i * 16 + lq * 4;
#pragma unroll
    for (int j = 0; j < 4; j++) {
      const int col = wn * 64 + j * 16 + lr;
      const float bv = bias[nloc0 + col];
      if (mode == 2) {
        const int m = m0 + row0;
        const int t = m >> 8, s = m & 255;
        ushort4 h;
        h.x = f2bf(acc[i][j][0] + bv);
        h.y = f2bf(acc[i][j][1] + bv);
        h.z = f2bf(acc[i][j][2] + bv);
        h.w = f2bf(acc[i][j][3] + bv);
        *(ushort4*)&featsT[((size_t)t * FF + nloc0 + col) * SS + s] = h;
      } else {
        unsigned short* outp = (mode == 0) ? theta : phi;
#pragma unroll
        for (int rr = 0; rr < 4; rr++)
          outp[(size_t)(m0 + row0 + rr) * AA + nloc0 + col] =
              f2bf(acc[i][j][rr] + bv);
      }
    }
  }
}

// ---------------------------------------------------------------------------
// Fused projection GEMM, fp32-A FALLBACK (used only if workspace too small).
// ---------------------------------------------------------------------------
__global__ __launch_bounds__(256) void k_proj(
    const float* __restrict__ batch,
    const unsigned short* __restrict__ aT,
    const unsigned short* __restrict__ bT,
    const unsigned short* __restrict__ gT,
    const float* __restrict__ a_b, const float* __restrict__ b_b,
    const float* __restrict__ g_b,
    unsigned short* __restrict__ theta,
    unsigned short* __restrict__ phi,
    unsigned short* __restrict__ featsT) {
  const int K = FF;
  __shared__ unsigned short As[128 * 32];
  __shared__ unsigned short Bs[128 * 32];

  const int nt = blockIdx.x, mt = blockIdx.y;
  const int m0 = mt * 128;
  const unsigned short* Wt;
  const float* bias;
  int nloc0, mode;
  if (nt < 2)      { Wt = aT; bias = a_b; nloc0 = nt * 128;       mode = 0; }
  else if (nt < 4) { Wt = bT; bias = b_b; nloc0 = (nt - 2) * 128; mode = 1; }
  else             { Wt = gT; bias = g_b; nloc0 = (nt - 4) * 128; mode = 2; }

  const int tid = threadIdx.x;
  const int lane = tid & 63, wave = tid >> 6;
  const int wm = wave >> 1, wn = wave & 1;
  const int lr = lane & 15, lq = lane >> 4;

  floatx4 acc[4][4];
#pragma unroll
  for (int i = 0; i < 4; i++)
#pragma unroll
    for (int j = 0; j < 4; j++) acc[i][j] = (floatx4)0.0f;

  for (int k0 = 0; k0 < K; k0 += 32) {
    __syncthreads();
    {
      int sl = tid;
      gl_lds16(Wt + (size_t)(nloc0 + (sl >> 2)) * K + k0 + (sl & 3) * 8,
               &Bs[wave * 512]);
      sl = tid + 256;
      gl_lds16(Wt + (size_t)(nloc0 + (sl >> 2)) * K + k0 + (sl & 3) * 8,
               &Bs[2048 + wave * 512]);
    }
#pragma unroll
    for (int sgi = 0; sgi < 4; sgi++) {
      int g = sgi * 256 + tid;
      int row = g >> 3, c4 = g & 7;
      const floatx4 v =
          *(const floatx4*)(batch + (size_t)(m0 + row) * K + k0 + c4 * 4);
      ushort4 h;
      h.x = f2bf(v.x); h.y = f2bf(v.y); h.z = f2bf(v.z); h.w = f2bf(v.w);
      *(ushort4*)&As[row * 32 + c4 * 4] = h;
    }
    __syncthreads();

    short8 af[4], bfr[4];
#pragma unroll
    for (int i = 0; i < 4; i++)
      af[i] = *(const short8*)&As[(wm * 64 + i * 16 + lr) * 32 + lq * 8];
#pragma unroll
    for (int j = 0; j < 4; j++)
      bfr[j] = *(const short8*)&Bs[(wn * 64 + j * 16 + lr) * 32 + lq * 8];
#pragma unroll
    for (int i = 0; i < 4; i++)
#pragma unroll
      for (int j = 0; j < 4; j++)
        acc[i][j] = __builtin_amdgcn_mfma_f32_16x16x32_bf16(af[i], bfr[j],
                                                            acc[i][j], 0, 0, 0);
  }

#pragma unroll
  for (int i = 0; i < 4; i++) {
    const int row0 = wm * 64 + i * 16 + lq * 4;
#pragma unroll
    for (int j = 0; j < 4; j++) {
      const int col = wn * 64 + j * 16 + lr;
      const float bv = bias[nloc0 + col];
      if (mode == 2) {
        const int m = m0 + row0;
        const int t = m >> 8, s = m & 255;
        ushort4 h;
        h.x = f2bf(acc[i][j][0] + bv);
        h.y = f2bf(acc[i][j][1] + bv);
        h.z = f2bf(acc[i][j][2] + bv);
        h.w = f2bf(acc[i][j][3] + bv);
        *(ushort4*)&featsT[((size_t)t * FF + nloc0 + col) * SS + s] = h;
      } else {
        unsigned short* outp = (mode == 0) ? theta : phi;
#pragma unroll
        for (int rr = 0; rr < 4; rr++)
          outp[(size_t)(m0 + row0 + rr) * AA + nloc0 + col] =
              f2bf(acc[i][j][rr] + bv);
      }
    }
  }
}

// ---------------------------------------------------------------------------
// Fused attn+apply, one block per (m-half, t):
//   Phase 1: P = theta[t][m0:m0+128][:] @ phi[t]^T        (128x256, bf16 in LDS)
//   Phase 2: out[t][m0:m0+128][:] = P @ featsT[t]^T / 512 (128x1024, fp32)
// P is XOR-swizzled (byte ^= (row&7)<<4) so phase-2 ds_read_b128 at row-stride
// 512 B is a free 2-way bank conflict instead of 16-way.
// LDS = 8 + 8 + 64 = 80 KB -> exactly 2 blocks/CU.
// ---------------------------------------------------------------------------
__global__ __launch_bounds__(256) void k_fused(
    const unsigned short* __restrict__ theta,
    const unsigned short* __restrict__ phi,
    const unsigned short* __restrict__ featsT,
    float* __restrict__ out) {
  __shared__ unsigned short As[128 * 32];
  __shared__ unsigned short Bs[128 * 32];
  __shared__ unsigned short P[128 * 256];  // 64 KB, swizzled

  const int mh = blockIdx.x, t = blockIdx.y;
  const int tid = threadIdx.x, lane = tid & 63, wave = tid >> 6;
  const int wm = wave >> 1, wn = wave & 1, lr = lane & 15, lq = lane >> 4;

  const unsigned short* Ath = theta + ((size_t)t * SS + mh * 128) * AA;
  const unsigned short* Bph = phi + (size_t)t * SS * AA;
  const unsigned short* Bft = featsT + (size_t)t * FF * SS;

  // ---- Phase 1: attn tile -> P (bf16, swizzled)
  for (int nb = 0; nb < 2; nb++) {
    floatx4 acc[4][4];
#pragma unroll
    for (int i = 0; i < 4; i++)
#pragma unroll
      for (int j = 0; j < 4; j++) acc[i][j] = (floatx4)0.0f;

    for (int k0 = 0; k0 < AA; k0 += 32) {
      __syncthreads();
      int sl = tid;
      gl_lds16(Ath + (size_t)(sl >> 2) * AA + k0 + (sl & 3) * 8,
               &As[wave * 512]);
      gl_lds16(Bph + (size_t)(nb * 128 + (sl >> 2)) * AA + k0 + (sl & 3) * 8,
               &Bs[wave * 512]);
      sl = tid + 256;
      gl_lds16(Ath + (size_t)(sl >> 2) * AA + k0 + (sl & 3) * 8,
               &As[2048 + wave * 512]);
      gl_lds16(Bph + (size_t)(nb * 128 + (sl >> 2)) * AA + k0 + (sl & 3) * 8,
               &Bs[2048 + wave * 512]);
      __syncthreads();

      short8 af[4], bfr[4];
#pragma unroll
      for (int i = 0; i < 4; i++)
        af[i] = *(const short8*)&As[(wm * 64 + i * 16 + lr) * 32 + lq * 8];
#pragma unroll
      for (int j = 0; j < 4; j++)
        bfr[j] = *(const short8*)&Bs[(wn * 64 + j * 16 + lr) * 32 + lq * 8];
#pragma unroll
      for (int i = 0; i < 4; i++)
#pragma unroll
        for (int j = 0; j < 4; j++)
          acc[i][j] = __builtin_amdgcn_mfma_f32_16x16x32_bf16(
              af[i], bfr[j], acc[i][j], 0, 0, 0);
    }

    // Write attn tile to P. C/D layout: col = lane&15, row = (lane>>4)*4+reg.
#pragma unroll
    for (int i = 0; i < 4; i++) {
#pragma unroll
      for (int j = 0; j < 4; j++) {
        const int colP = nb * 128 + wn * 64 + j * 16 + lr;
#pragma unroll
        for (int rr = 0; rr < 4; rr++) {
          const int rowP = wm * 64 + i * 16 + lq * 4 + rr;
          const unsigned off =
              ((unsigned)(rowP * 256 + colP) * 2u) ^ ((unsigned)(rowP & 7) << 4);
          *(unsigned short*)((char*)P + off) = f2bf(acc[i][j][rr]);
        }
      }
    }
  }
  // P fully written; phase-2 loop-top barrier orders writes vs reads.

  // ---- Phase 2: out = P @ featsT^T / 512
  const float inv = 1.0f / 512.0f;
  float* Ob = out + ((size_t)t * SS + mh * 128) * FF;
  for (int nf = 0; nf < 8; nf++) {
    floatx4 acc[4][4];
#pragma unroll
    for (int i = 0; i < 4; i++)
#pragma unroll
      for (int j = 0; j < 4; j++) acc[i][j] = (floatx4)0.0f;

    for (int k0 = 0; k0 < SS; k0 += 32) {
      __syncthreads();
      int sl = tid;
      gl_lds16(Bft + (size_t)(nf * 128 + (sl >> 2)) * SS + k0 + (sl & 3) * 8,
               &Bs[wave * 512]);
      sl = tid + 256;
      gl_lds16(Bft + (size_t)(nf * 128 + (sl >> 2)) * SS + k0 + (sl & 3) * 8,
               &Bs[2048 + wave * 512]);
      __syncthreads();

      short8 af[4], bfr[4];
#pragma unroll
      for (int i = 0; i < 4; i++) {
        const int rowP = wm * 64 + i * 16 + lr;
        const unsigned off = ((unsigned)(rowP * 256 + k0 + lq * 8) * 2u) ^
                             ((unsigned)(rowP & 7) << 4);
        af[i] = *(const short8*)((const char*)P + off);
      }
#pragma unroll
      for (int j = 0; j < 4; j++)
        bfr[j] = *(const short8*)&Bs[(wn * 64 + j * 16 + lr) * 32 + lq * 8];
#pragma unroll
      for (int i = 0; i < 4; i++)
#pragma unroll
        for (int j = 0; j < 4; j++)
          acc[i][j] = __builtin_amdgcn_mfma_f32_16x16x32_bf16(
              af[i], bfr[j], acc[i][j], 0, 0, 0);
    }

#pragma unroll
    for (int i = 0; i < 4; i++) {
      const int row0 = wm * 64 + i * 16 + lq * 4;
#pragma unroll
      for (int j = 0; j < 4; j++) {
        const int col = nf * 128 + wn * 64 + j * 16 + lr;
#pragma unroll
        for (int rr = 0; rr < 4; rr++)
          Ob[(size_t)(row0 + rr) * FF + col] = acc[i][j][rr] * inv;
      }
    }
  }
}

// ---------------------------------------------------------------------------
extern "C" void kernel_launch(void* const* d_in, const int* in_sizes, int n_in,
                              void* d_out, int out_size, void* d_ws,
                              size_t ws_size, hipStream_t stream) {
  const float* batch = (const float*)d_in[0];
  const float* a_w   = (const float*)d_in[1];
  const float* a_b   = (const float*)d_in[2];
  const float* b_w   = (const float*)d_in[3];
  const float* b_b   = (const float*)d_in[4];
  const float* g_w   = (const float*)d_in[5];
  const float* g_b   = (const float*)d_in[6];
  float* out = (float*)d_out;

  // Workspace layout (bf16 elements). attn buffer no longer needed.
  unsigned short* ws      = (unsigned short*)d_ws;
  unsigned short* aT      = ws;                                  // 256x1024
  unsigned short* bT      = aT + (size_t)AA * FF;                // 256x1024
  unsigned short* gT      = bT + (size_t)AA * FF;                // 1024x1024
  unsigned short* theta   = gT + (size_t)FF * FF;                // 65536x256
  unsigned short* phi     = theta + (size_t)TT * SS * AA;        // 65536x256
  unsigned short* featsT  = phi + (size_t)TT * SS * AA;          // [t][f][s]
  unsigned short* batch16 = featsT + (size_t)TT * FF * SS;       // 65536x1024

  const size_t need_b16 =
      ((size_t)2 * AA * FF + (size_t)FF * FF + (size_t)2 * TT * SS * AA +
       (size_t)TT * FF * SS + (size_t)TT * SS * FF) *
      sizeof(unsigned short);

  dim3 tb(32, 8);
  k_transpose_cvt<<<dim3(32, 8),  tb, 0, stream>>>(a_w, aT, FF, AA);
  k_transpose_cvt<<<dim3(32, 8),  tb, 0, stream>>>(b_w, bT, FF, AA);
  k_transpose_cvt<<<dim3(32, 32), tb, 0, stream>>>(g_w, gT, FF, FF);

  if (ws_size >= need_b16) {
    // One-shot batch fp32->bf16 (memory-bound), then pure-DMA projection GEMM.
    k_cvt_bf16<<<2048, 256, 0, stream>>>(batch, batch16,
                                         (long)TT * SS * FF / 8);
    k_proj_b16<<<dim3(12, 512), 256, 0, stream>>>(batch16, aT, bT, gT, a_b,
                                                  b_b, g_b, theta, phi,
                                                  featsT);
  } else {
    // Fallback: fp32 in-kernel staging (previous verified path).
    k_proj<<<dim3(12, 512), 256, 0, stream>>>(batch, aT, bT, gT, a_b, b_b,
                                              g_b, theta, phi, featsT);
  }

  // Fused attn + apply: one block per (m-half, t); no attn round-trip.
  k_fused<<<dim3(2, TT), 256, 0, stream>>>(theta, phi, featsT, out);
}

// Round 3
// 898.308 us; speedup vs baseline: 1.0798x; 1.0798x over previous
//
#include <hip/hip_runtime.h>
#include <stdint.h>

// Problem dims (fixed by the reference)
#define TT 256
#define SS 256
#define FF 1024
#define AA 256

typedef __attribute__((ext_vector_type(8))) short short8;
typedef __attribute__((ext_vector_type(8))) unsigned short ushort8v;
typedef __attribute__((ext_vector_type(4))) float floatx4;

// fp32 -> bf16 round-to-nearest-even
__device__ __forceinline__ unsigned short f2bf(float f) {
  unsigned int u = __float_as_uint(f);
  u += 0x7FFFu + ((u >> 16) & 1u);
  return (unsigned short)(u >> 16);
}

// async global->LDS, 16 B per lane; LDS dest = wave-uniform base + lane*16
__device__ __forceinline__ void gl_lds16(const unsigned short* g, unsigned short* l) {
  __builtin_amdgcn_global_load_lds(
      (__attribute__((address_space(1))) void*)(g),
      (__attribute__((address_space(3))) void*)(l), 16, 0, 0);
}

// ---------------------------------------------------------------------------
// Whole-tensor fp32 -> bf16 convert (memory-bound pre-pass for batch).
// ---------------------------------------------------------------------------
__global__ __launch_bounds__(256) void k_cvt_bf16(const float* __restrict__ in,
                                                  unsigned short* __restrict__ out,
                                                  long n8) {
  long i = (long)blockIdx.x * 256 + threadIdx.x;
  const long stride = (long)gridDim.x * 256;
  for (; i < n8; i += stride) {
    const floatx4 v0 = *(const floatx4*)(in + i * 8);
    const floatx4 v1 = *(const floatx4*)(in + i * 8 + 4);
    ushort8v h;
    h[0] = f2bf(v0.x); h[1] = f2bf(v0.y); h[2] = f2bf(v0.z); h[3] = f2bf(v0.w);
    h[4] = f2bf(v1.x); h[5] = f2bf(v1.y); h[6] = f2bf(v1.z); h[7] = f2bf(v1.w);
    *(ushort8v*)(out + i * 8) = h;
  }
}

// ---------------------------------------------------------------------------
// Weight transpose + fp32->bf16:  WT[n][k] = bf16(W[k][n]).  W: K x N fp32.
// ---------------------------------------------------------------------------
__global__ void k_transpose_cvt(const float* __restrict__ W,
                                unsigned short* __restrict__ WT,
                                int K, int N) {
  __shared__ float tile[32][33];
  const int bk = blockIdx.x * 32, bn = blockIdx.y * 32;
  const int tx = threadIdx.x, ty = threadIdx.y;
  for (int i = ty; i < 32; i += 8)
    tile[i][tx] = W[(size_t)(bk + i) * N + bn + tx];
  __syncthreads();
  for (int i = ty; i < 32; i += 8)
    WT[(size_t)(bn + i) * K + bk + tx] = f2bf(tile[tx][i]);
}

// ---------------------------------------------------------------------------
// Fused projection GEMM, bf16-A, 2-phase double-buffered (T3-minimum):
//   STAGE(next k-tile) -> compute(cur) -> one __syncthreads per iter
//   (the barrier's implicit vmcnt(0) drains loads issued a compute-phase ago).
// XCD-chunked 1-D grid (T1): lin -> xcd = lin&7 owns mt in [xcd*64, xcd*64+64),
// nt fastest within chunk -> the 12 same-A-panel blocks run back-to-back on
// one XCD's L2 (kills the 4x batch16 HBM re-fetch).
//   n-tile 0..1 -> theta ; 2..3 -> phi ; 4..11 -> featsT[t][f][s]
// ---------------------------------------------------------------------------
__global__ __launch_bounds__(256) void k_proj_b16(
    const unsigned short* __restrict__ batch16,
    const unsigned short* __restrict__ aT,
    const unsigned short* __restrict__ bT,
    const unsigned short* __restrict__ gT,
    const float* __restrict__ a_b, const float* __restrict__ b_b,
    const float* __restrict__ g_b,
    unsigned short* __restrict__ theta,
    unsigned short* __restrict__ phi,
    unsigned short* __restrict__ featsT) {
  const int K = FF;  // 1024
  __shared__ unsigned short As[2][128 * 32];
  __shared__ unsigned short Bs[2][128 * 32];

  // Bijective swizzle: 6144 = 8 xcd * 64 mt * 12 nt
  const int lin = blockIdx.x;
  const int xcd = lin & 7, idx = lin >> 3;  // idx in [0,768)
  const int nt = idx % 12;
  const int mt = xcd * 64 + idx / 12;       // [0,512)
  const int m0 = mt * 128;

  const unsigned short* Wt;
  const float* bias;
  int nloc0, mode;  // mode: 0 theta, 1 phi, 2 featsT
  if (nt < 2)      { Wt = aT; bias = a_b; nloc0 = nt * 128;       mode = 0; }
  else if (nt < 4) { Wt = bT; bias = b_b; nloc0 = (nt - 2) * 128; mode = 1; }
  else             { Wt = gT; bias = g_b; nloc0 = (nt - 4) * 128; mode = 2; }

  const int tid = threadIdx.x;
  const int lane = tid & 63, wave = tid >> 6;
  const int wm = wave >> 1, wn = wave & 1;
  const int lr = lane & 15, lq = lane >> 4;

  floatx4 acc[4][4];
#pragma unroll
  for (int i = 0; i < 4; i++)
#pragma unroll
    for (int j = 0; j < 4; j++) acc[i][j] = (floatx4)0.0f;

#define STAGE_PROJ(b_, k0_)                                                   \
  do {                                                                        \
    int sl = tid;                                                             \
    gl_lds16(batch16 + (size_t)(m0 + (sl >> 2)) * K + (k0_) + (sl & 3) * 8,   \
             &As[b_][wave * 512]);                                            \
    gl_lds16(Wt + (size_t)(nloc0 + (sl >> 2)) * K + (k0_) + (sl & 3) * 8,     \
             &Bs[b_][wave * 512]);                                            \
    sl = tid + 256;                                                           \
    gl_lds16(batch16 + (size_t)(m0 + (sl >> 2)) * K + (k0_) + (sl & 3) * 8,   \
             &As[b_][2048 + wave * 512]);                                     \
    gl_lds16(Wt + (size_t)(nloc0 + (sl >> 2)) * K + (k0_) + (sl & 3) * 8,     \
             &Bs[b_][2048 + wave * 512]);                                     \
  } while (0)

  STAGE_PROJ(0, 0);
  __syncthreads();  // drains vmcnt(0): buf0 ready
  int cur = 0;
  for (int k0 = 0; k0 < K; k0 += 32) {
    if (k0 + 32 < K) STAGE_PROJ(cur ^ 1, k0 + 32);  // prefetch next tile

    short8 af[4], bfr[4];
#pragma unroll
    for (int i = 0; i < 4; i++)
      af[i] = *(const short8*)&As[cur][(wm * 64 + i * 16 + lr) * 32 + lq * 8];
#pragma unroll
    for (int j = 0; j < 4; j++)
      bfr[j] = *(const short8*)&Bs[cur][(wn * 64 + j * 16 + lr) * 32 + lq * 8];
#pragma unroll
    for (int i = 0; i < 4; i++)
#pragma unroll
      for (int j = 0; j < 4; j++)
        acc[i][j] = __builtin_amdgcn_mfma_f32_16x16x32_bf16(af[i], bfr[j],
                                                            acc[i][j], 0, 0, 0);
    __syncthreads();  // next buf staged + all reads of cur done
    cur ^= 1;
  }
#undef STAGE_PROJ

  // Epilogue. C/D layout: col = lane&15, row = (lane>>4)*4 + reg.
#pragma unroll
  for (int i = 0; i < 4; i++) {
    const int row0 = wm * 64 + i * 16 + lq * 4;
#pragma unroll
    for (int j = 0; j < 4; j++) {
      const int col = wn * 64 + j * 16 + lr;
      const float bv = bias[nloc0 + col];
      if (mode == 2) {
        const int m = m0 + row0;
        const int t = m >> 8, s = m & 255;
        ushort4 h;
        h.x = f2bf(acc[i][j][0] + bv);
        h.y = f2bf(acc[i][j][1] + bv);
        h.z = f2bf(acc[i][j][2] + bv);
        h.w = f2bf(acc[i][j][3] + bv);
        *(ushort4*)&featsT[((size_t)t * FF + nloc0 + col) * SS + s] = h;
      } else {
        unsigned short* outp = (mode == 0) ? theta : phi;
#pragma unroll
        for (int rr = 0; rr < 4; rr++)
          outp[(size_t)(m0 + row0 + rr) * AA + nloc0 + col] =
              f2bf(acc[i][j][rr] + bv);
      }
    }
  }
}

// ---------------------------------------------------------------------------
// Fused projection GEMM, fp32-A FALLBACK (used only if workspace too small).
// ---------------------------------------------------------------------------
__global__ __launch_bounds__(256) void k_proj(
    const float* __restrict__ batch,
    const unsigned short* __restrict__ aT,
    const unsigned short* __restrict__ bT,
    const unsigned short* __restrict__ gT,
    const float* __restrict__ a_b, const float* __restrict__ b_b,
    const float* __restrict__ g_b,
    unsigned short* __restrict__ theta,
    unsigned short* __restrict__ phi,
    unsigned short* __restrict__ featsT) {
  const int K = FF;
  __shared__ unsigned short As[128 * 32];
  __shared__ unsigned short Bs[128 * 32];

  const int nt = blockIdx.x, mt = blockIdx.y;
  const int m0 = mt * 128;
  const unsigned short* Wt;
  const float* bias;
  int nloc0, mode;
  if (nt < 2)      { Wt = aT; bias = a_b; nloc0 = nt * 128;       mode = 0; }
  else if (nt < 4) { Wt = bT; bias = b_b; nloc0 = (nt - 2) * 128; mode = 1; }
  else             { Wt = gT; bias = g_b; nloc0 = (nt - 4) * 128; mode = 2; }

  const int tid = threadIdx.x;
  const int lane = tid & 63, wave = tid >> 6;
  const int wm = wave >> 1, wn = wave & 1;
  const int lr = lane & 15, lq = lane >> 4;

  floatx4 acc[4][4];
#pragma unroll
  for (int i = 0; i < 4; i++)
#pragma unroll
    for (int j = 0; j < 4; j++) acc[i][j] = (floatx4)0.0f;

  for (int k0 = 0; k0 < K; k0 += 32) {
    __syncthreads();
    {
      int sl = tid;
      gl_lds16(Wt + (size_t)(nloc0 + (sl >> 2)) * K + k0 + (sl & 3) * 8,
               &Bs[wave * 512]);
      sl = tid + 256;
      gl_lds16(Wt + (size_t)(nloc0 + (sl >> 2)) * K + k0 + (sl & 3) * 8,
               &Bs[2048 + wave * 512]);
    }
#pragma unroll
    for (int sgi = 0; sgi < 4; sgi++) {
      int g = sgi * 256 + tid;
      int row = g >> 3, c4 = g & 7;
      const floatx4 v =
          *(const floatx4*)(batch + (size_t)(m0 + row) * K + k0 + c4 * 4);
      ushort4 h;
      h.x = f2bf(v.x); h.y = f2bf(v.y); h.z = f2bf(v.z); h.w = f2bf(v.w);
      *(ushort4*)&As[row * 32 + c4 * 4] = h;
    }
    __syncthreads();

    short8 af[4], bfr[4];
#pragma unroll
    for (int i = 0; i < 4; i++)
      af[i] = *(const short8*)&As[(wm * 64 + i * 16 + lr) * 32 + lq * 8];
#pragma unroll
    for (int j = 0; j < 4; j++)
      bfr[j] = *(const short8*)&Bs[(wn * 64 + j * 16 + lr) * 32 + lq * 8];
#pragma unroll
    for (int i = 0; i < 4; i++)
#pragma unroll
      for (int j = 0; j < 4; j++)
        acc[i][j] = __builtin_amdgcn_mfma_f32_16x16x32_bf16(af[i], bfr[j],
                                                            acc[i][j], 0, 0, 0);
  }

#pragma unroll
  for (int i = 0; i < 4; i++) {
    const int row0 = wm * 64 + i * 16 + lq * 4;
#pragma unroll
    for (int j = 0; j < 4; j++) {
      const int col = wn * 64 + j * 16 + lr;
      const float bv = bias[nloc0 + col];
      if (mode == 2) {
        const int m = m0 + row0;
        const int t = m >> 8, s = m & 255;
        ushort4 h;
        h.x = f2bf(acc[i][j][0] + bv);
        h.y = f2bf(acc[i][j][1] + bv);
        h.z = f2bf(acc[i][j][2] + bv);
        h.w = f2bf(acc[i][j][3] + bv);
        *(ushort4*)&featsT[((size_t)t * FF + nloc0 + col) * SS + s] = h;
      } else {
        unsigned short* outp = (mode == 0) ? theta : phi;
#pragma unroll
        for (int rr = 0; rr < 4; rr++)
          outp[(size_t)(m0 + row0 + rr) * AA + nloc0 + col] =
              f2bf(acc[i][j][rr] + bv);
      }
    }
  }
}

// ---------------------------------------------------------------------------
// Fused attn+apply, one block per (t, m-half), XCD-chunked grid:
//   Phase 1: P = theta[t][m0:m0+128][:] @ phi[t]^T        (128x256, bf16 in LDS)
//   Phase 2: out[t][m0:m0+128][:] = P @ featsT[t]^T / 512 (2-phase dbuf,
//            ping-ponging between As and Bs; A-frags come from LDS P)
// P XOR-swizzled (byte ^= (row&7)<<4): phase-2 row-stride-512B ds_read_b128
// is a free 2-way conflict. LDS = 8 + 8 + 64 = 80 KB -> 2 blocks/CU.
// ---------------------------------------------------------------------------
__global__ __launch_bounds__(256) void k_fused(
    const unsigned short* __restrict__ theta,
    const unsigned short* __restrict__ phi,
    const unsigned short* __restrict__ featsT,
    float* __restrict__ out) {
  __shared__ unsigned short As[128 * 32];
  __shared__ unsigned short Bs[128 * 32];
  __shared__ unsigned short P[128 * 256];  // 64 KB, swizzled

  // Bijective swizzle: 512 = 8 xcd * 32 t * 2 mh; both mh of a t adjacent
  // on the same XCD -> featsT[t]/phi[t] shared in that XCD's L2.
  const int lin = blockIdx.x;
  const int xcd = lin & 7, idx = lin >> 3;  // idx in [0,64)
  const int t = xcd * 32 + (idx >> 1);
  const int mh = idx & 1;

  const int tid = threadIdx.x, lane = tid & 63, wave = tid >> 6;
  const int wm = wave >> 1, wn = wave & 1, lr = lane & 15, lq = lane >> 4;

  const unsigned short* Ath = theta + ((size_t)t * SS + mh * 128) * AA;
  const unsigned short* Bph = phi + (size_t)t * SS * AA;
  const unsigned short* Bft = featsT + (size_t)t * FF * SS;

  // ---- Phase 1: attn tile -> P (bf16, swizzled)
  for (int nb = 0; nb < 2; nb++) {
    floatx4 acc[4][4];
#pragma unroll
    for (int i = 0; i < 4; i++)
#pragma unroll
      for (int j = 0; j < 4; j++) acc[i][j] = (floatx4)0.0f;

    for (int k0 = 0; k0 < AA; k0 += 32) {
      __syncthreads();
      int sl = tid;
      gl_lds16(Ath + (size_t)(sl >> 2) * AA + k0 + (sl & 3) * 8,
               &As[wave * 512]);
      gl_lds16(Bph + (size_t)(nb * 128 + (sl >> 2)) * AA + k0 + (sl & 3) * 8,
               &Bs[wave * 512]);
      sl = tid + 256;
      gl_lds16(Ath + (size_t)(sl >> 2) * AA + k0 + (sl & 3) * 8,
               &As[2048 + wave * 512]);
      gl_lds16(Bph + (size_t)(nb * 128 + (sl >> 2)) * AA + k0 + (sl & 3) * 8,
               &Bs[2048 + wave * 512]);
      __syncthreads();

      short8 af[4], bfr[4];
#pragma unroll
      for (int i = 0; i < 4; i++)
        af[i] = *(const short8*)&As[(wm * 64 + i * 16 + lr) * 32 + lq * 8];
#pragma unroll
      for (int j = 0; j < 4; j++)
        bfr[j] = *(const short8*)&Bs[(wn * 64 + j * 16 + lr) * 32 + lq * 8];
#pragma unroll
      for (int i = 0; i < 4; i++)
#pragma unroll
        for (int j = 0; j < 4; j++)
          acc[i][j] = __builtin_amdgcn_mfma_f32_16x16x32_bf16(
              af[i], bfr[j], acc[i][j], 0, 0, 0);
    }

    // Write attn tile to P. C/D layout: col = lane&15, row = (lane>>4)*4+reg.
    // Per-wave quadrants are disjoint -> no race.
#pragma unroll
    for (int i = 0; i < 4; i++) {
#pragma unroll
      for (int j = 0; j < 4; j++) {
        const int colP = nb * 128 + wn * 64 + j * 16 + lr;
#pragma unroll
        for (int rr = 0; rr < 4; rr++) {
          const int rowP = wm * 64 + i * 16 + lq * 4 + rr;
          const unsigned off =
              ((unsigned)(rowP * 256 + colP) * 2u) ^ ((unsigned)(rowP & 7) << 4);
          *(unsigned short*)((char*)P + off) = f2bf(acc[i][j][rr]);
        }
      }
    }
  }
  __syncthreads();  // all phase-1 reads of As/Bs done; P writes ordered

  // ---- Phase 2: out = P @ featsT^T / 512, 2-phase dbuf (As <-> Bs)
#define STAGE_F2(dst_, nf_, k0_)                                              \
  do {                                                                        \
    int sl = tid;                                                             \
    gl_lds16(Bft + (size_t)((nf_) * 128 + (sl >> 2)) * SS + (k0_) +           \
                 (sl & 3) * 8,                                                \
             &(dst_)[wave * 512]);                                            \
    sl = tid + 256;                                                           \
    gl_lds16(Bft + (size_t)((nf_) * 128 + (sl >> 2)) * SS + (k0_) +           \
                 (sl & 3) * 8,                                                \
             &(dst_)[2048 + wave * 512]);                                     \
  } while (0)

  STAGE_F2(As, 0, 0);
  __syncthreads();  // buf(As) ready; also publishes P
  int cur = 0;      // 0 -> As holds current tile, 1 -> Bs

  const float inv = 1.0f / 512.0f;
  float* Ob = out + ((size_t)t * SS + mh * 128) * FF;
  for (int nf = 0; nf < 8; nf++) {
    floatx4 acc[4][4];
#pragma unroll
    for (int i = 0; i < 4; i++)
#pragma unroll
      for (int j = 0; j < 4; j++) acc[i][j] = (floatx4)0.0f;

    for (int k0 = 0; k0 < SS; k0 += 32) {
      int nnf = nf, nk = k0 + 32;
      if (nk == SS) { nnf++; nk = 0; }
      if (nnf < 8) {
        unsigned short* nxt = (cur == 0) ? Bs : As;
        STAGE_F2(nxt, nnf, nk);  // prefetch next tile
      }
      const unsigned short* curb = (cur == 0) ? As : Bs;

      short8 af[4], bfr[4];
#pragma unroll
      for (int i = 0; i < 4; i++) {
        const int rowP = wm * 64 + i * 16 + lr;
        const unsigned off = ((unsigned)(rowP * 256 + k0 + lq * 8) * 2u) ^
                             ((unsigned)(rowP & 7) << 4);
        af[i] = *(const short8*)((const char*)P + off);
      }
#pragma unroll
      for (int j = 0; j < 4; j++)
        bfr[j] = *(const short8*)&curb[(wn * 64 + j * 16 + lr) * 32 + lq * 8];
#pragma unroll
      for (int i = 0; i < 4; i++)
#pragma unroll
        for (int j = 0; j < 4; j++)
          acc[i][j] = __builtin_amdgcn_mfma_f32_16x16x32_bf16(
              af[i], bfr[j], acc[i][j], 0, 0, 0);
      __syncthreads();
      cur ^= 1;
    }
#undef STAGE_F2

#pragma unroll
    for (int i = 0; i < 4; i++) {
      const int row0 = wm * 64 + i * 16 + lq * 4;
#pragma unroll
      for (int j = 0; j < 4; j++) {
        const int col = nf * 128 + wn * 64 + j * 16 + lr;
#pragma unroll
        for (int rr = 0; rr < 4; rr++)
          Ob[(size_t)(row0 + rr) * FF + col] = acc[i][j][rr] * inv;
      }
    }
  }
}

// ---------------------------------------------------------------------------
extern "C" void kernel_launch(void* const* d_in, const int* in_sizes, int n_in,
                              void* d_out, int out_size, void* d_ws,
                              size_t ws_size, hipStream_t stream) {
  const float* batch = (const float*)d_in[0];
  const float* a_w   = (const float*)d_in[1];
  const float* a_b   = (const float*)d_in[2];
  const float* b_w   = (const float*)d_in[3];
  const float* b_b   = (const float*)d_in[4];
  const float* g_w   = (const float*)d_in[5];
  const float* g_b   = (const float*)d_in[6];
  float* out = (float*)d_out;

  // Workspace layout (bf16 elements).
  unsigned short* ws      = (unsigned short*)d_ws;
  unsigned short* aT      = ws;                                  // 256x1024
  unsigned short* bT      = aT + (size_t)AA * FF;                // 256x1024
  unsigned short* gT      = bT + (size_t)AA * FF;                // 1024x1024
  unsigned short* theta   = gT + (size_t)FF * FF;                // 65536x256
  unsigned short* phi     = theta + (size_t)TT * SS * AA;        // 65536x256
  unsigned short* featsT  = phi + (size_t)TT * SS * AA;          // [t][f][s]
  unsigned short* batch16 = featsT + (size_t)TT * FF * SS;       // 65536x1024

  const size_t need_b16 =
      ((size_t)2 * AA * FF + (size_t)FF * FF + (size_t)2 * TT * SS * AA +
       (size_t)TT * FF * SS + (size_t)TT * SS * FF) *
      sizeof(unsigned short);

  dim3 tb(32, 8);
  k_transpose_cvt<<<dim3(32, 8),  tb, 0, stream>>>(a_w, aT, FF, AA);
  k_transpose_cvt<<<dim3(32, 8),  tb, 0, stream>>>(b_w, bT, FF, AA);
  k_transpose_cvt<<<dim3(32, 32), tb, 0, stream>>>(g_w, gT, FF, FF);

  if (ws_size >= need_b16) {
    // One-shot batch fp32->bf16 (memory-bound), then pure-DMA projection GEMM.
    k_cvt_bf16<<<2048, 256, 0, stream>>>(batch, batch16,
                                         (long)TT * SS * FF / 8);
    k_proj_b16<<<dim3(6144), 256, 0, stream>>>(batch16, aT, bT, gT, a_b,
                                               b_b, g_b, theta, phi, featsT);
  } else {
    // Fallback: fp32 in-kernel staging (previous verified path).
    k_proj<<<dim3(12, 512), 256, 0, stream>>>(batch, aT, bT, gT, a_b, b_b,
                                              g_b, theta, phi, featsT);
  }

  // Fused attn + apply: one block per (t, m-half); no attn round-trip.
  k_fused<<<dim3(512), 256, 0, stream>>>(theta, phi, featsT, out);
}

// Round 4
// 839.239 us; speedup vs baseline: 1.1558x; 1.0704x over previous
//
#include <hip/hip_runtime.h>
#include <stdint.h>

// Problem dims (fixed by the reference)
#define TT 256
#define SS 256
#define FF 1024
#define AA 256

typedef __attribute__((ext_vector_type(8))) short short8;
typedef __attribute__((ext_vector_type(8))) unsigned short ushort8v;
typedef __attribute__((ext_vector_type(4))) float floatx4;

// fp32 -> bf16 round-to-nearest-even
__device__ __forceinline__ unsigned short f2bf(float f) {
  unsigned int u = __float_as_uint(f);
  u += 0x7FFFu + ((u >> 16) & 1u);
  return (unsigned short)(u >> 16);
}

// async global->LDS, 16 B per lane; LDS dest = wave-uniform base + lane*16
__device__ __forceinline__ void gl_lds16(const unsigned short* g, unsigned short* l) {
  __builtin_amdgcn_global_load_lds(
      (__attribute__((address_space(1))) void*)(g),
      (__attribute__((address_space(3))) void*)(l), 16, 0, 0);
}

// swizzled LDS fragment read: logical (row, 16B-col lq) of a [128][32] bf16
// half-tile; phys byte = logical ^ ((bit9)<<5)  (st_16x32)
__device__ __forceinline__ short8 frag_ld(const unsigned short* base, int row,
                                          int lq) {
  unsigned l = (unsigned)(row * 64 + lq * 16);
  l ^= ((l >> 9) & 1u) << 5;
  return *(const short8*)((const char*)base + l);
}

// ---------------------------------------------------------------------------
// Whole-tensor fp32 -> bf16 convert (memory-bound pre-pass for batch).
// ---------------------------------------------------------------------------
__global__ __launch_bounds__(256) void k_cvt_bf16(const float* __restrict__ in,
                                                  unsigned short* __restrict__ out,
                                                  long n8) {
  long i = (long)blockIdx.x * 256 + threadIdx.x;
  const long stride = (long)gridDim.x * 256;
  for (; i < n8; i += stride) {
    const floatx4 v0 = *(const floatx4*)(in + i * 8);
    const floatx4 v1 = *(const floatx4*)(in + i * 8 + 4);
    ushort8v h;
    h[0] = f2bf(v0.x); h[1] = f2bf(v0.y); h[2] = f2bf(v0.z); h[3] = f2bf(v0.w);
    h[4] = f2bf(v1.x); h[5] = f2bf(v1.y); h[6] = f2bf(v1.z); h[7] = f2bf(v1.w);
    *(ushort8v*)(out + i * 8) = h;
  }
}

// ---------------------------------------------------------------------------
// Weight transpose + fp32->bf16:  WT[n][k] = bf16(W[k][n]).  W: K x N fp32.
// ---------------------------------------------------------------------------
__global__ void k_transpose_cvt(const float* __restrict__ W,
                                unsigned short* __restrict__ WT,
                                int K, int N) {
  __shared__ float tile[32][33];
  const int bk = blockIdx.x * 32, bn = blockIdx.y * 32;
  const int tx = threadIdx.x, ty = threadIdx.y;
  for (int i = ty; i < 32; i += 8)
    tile[i][tx] = W[(size_t)(bk + i) * N + bn + tx];
  __syncthreads();
  for (int i = ty; i < 32; i += 8)
    WT[(size_t)(bn + i) * K + bk + tx] = f2bf(tile[tx][i]);
}

// ---------------------------------------------------------------------------
// Projection GEMM, 256x256 tile, counted-vmcnt pipeline (T1+T2+T3+T4+T5):
//   - 8 waves (2M x 4N), per-wave 128x64 output, BK=32, K=1024 -> 32 K-tiles
//   - 3-deep LDS ring per tensor (3 slots x 2 halves x [128][32] bf16 = 48 KB
//     each, 96 KB total): staging runs 2 K-tiles ahead of compute, so the
//     per-tile wait is vmcnt(4) (tile j+2's 4 loads stay in flight), never 0.
//   - st_16x32 XOR swizzle on LDS: inverse-swizzled global_load_lds SOURCE +
//     swizzled ds_read address (rule: both-sides-or-neither).
//   - raw s_barrier (no implicit vmcnt drain), setprio(1) around MFMA.
//   n-tile 0 -> theta, 1 -> phi, 2..5 -> featsT[t][f][s]
// ---------------------------------------------------------------------------
__global__ __launch_bounds__(512, 2) void k_proj8(
    const unsigned short* __restrict__ batch16,
    const unsigned short* __restrict__ aT,
    const unsigned short* __restrict__ bT,
    const unsigned short* __restrict__ gT,
    const float* __restrict__ a_b, const float* __restrict__ b_b,
    const float* __restrict__ g_b,
    unsigned short* __restrict__ theta,
    unsigned short* __restrict__ phi,
    unsigned short* __restrict__ featsT) {
  const int K = FF;  // 1024
  __shared__ unsigned short Al[3][2][4096];  // [slot][m-half][128*32]
  __shared__ unsigned short Bl[3][2][4096];  // [slot][n-half][128*32]

  // XCD-chunked bijective grid: 1536 = 8 xcd * 32 mt * 6 nt, nt fastest
  // -> the 6 same-A-panel blocks are adjacent on one XCD's L2.
  const int lin = blockIdx.x;
  const int xcd = lin / 192, idx = lin - xcd * 192;
  const int nt = idx % 6;
  const int mt = xcd * 32 + idx / 6;
  const int m0 = mt * 256;

  const unsigned short* Wt;
  const float* bias;
  int mode, nf0 = 0;  // mode: 0 theta, 1 phi, 2 featsT
  if (nt == 0)      { Wt = aT; bias = a_b; mode = 0; }
  else if (nt == 1) { Wt = bT; bias = b_b; mode = 1; }
  else { nf0 = (nt - 2) * 256; Wt = gT + (size_t)nf0 * K; bias = g_b + nf0; mode = 2; }

  const int tid = threadIdx.x;
  const int lane = tid & 63, wave = tid >> 6;
  const int wm = wave >> 2, wn = wave & 3;   // 2 x 4 wave grid
  const int lr = lane & 15, lq = lane >> 4;
  const int bh = wn >> 1;                    // which B half this wave reads
  const int bn0 = (wn & 1) * 64;             // row base within B half

  // Staging source coords: LDS dest is linear (chunk = tid*16B); the SOURCE
  // is inverse-swizzled so that swizzled reads see logical data (involution).
  const unsigned o = (unsigned)tid * 16u;
  const unsigned lo = o ^ (((o >> 9) & 1u) << 5);
  const int srow = (int)(lo >> 6);          // 0..127
  const int scol = (int)((lo & 63u) >> 1);  // 0..31, step 8
  const size_t aOff0 = (size_t)(m0 + srow) * K + scol;
  const size_t aOff1 = (size_t)(m0 + 128 + srow) * K + scol;
  const size_t bOff0 = (size_t)srow * K + scol;
  const size_t bOff1 = (size_t)(128 + srow) * K + scol;
  const int ldsb = wave * 512;  // wave-uniform dest base (elems)

#define STG_A(s_, k_)                                    \
  do {                                                   \
    gl_lds16(batch16 + aOff0 + (k_), &Al[s_][0][ldsb]);  \
    gl_lds16(batch16 + aOff1 + (k_), &Al[s_][1][ldsb]);  \
  } while (0)
#define STG_B(s_, k_)                              \
  do {                                             \
    gl_lds16(Wt + bOff0 + (k_), &Bl[s_][0][ldsb]); \
    gl_lds16(Wt + bOff1 + (k_), &Bl[s_][1][ldsb]); \
  } while (0)

  floatx4 acc[8][4];
#pragma unroll
  for (int i = 0; i < 8; i++)
#pragma unroll
    for (int j = 0; j < 4; j++) acc[i][j] = (floatx4)0.0f;

  // Prologue: stage K-tiles 0 and 1; wait for tile 0 only (tile 1 in flight).
  STG_A(0, 0);  STG_B(0, 0);
  STG_A(1, 32); STG_B(1, 32);
  asm volatile("s_waitcnt vmcnt(4)" ::: "memory");
  __builtin_amdgcn_s_barrier();

  int sl = 0, sl2 = 2;
  for (int j = 0; j < 32; ++j) {
    const unsigned short* Ah = Al[sl][wm];
    const unsigned short* Bh = Bl[sl][bh];
    const int k2 = j * 32 + 64;     // k0 of tile j+2
    const bool pf = (j < 30);

    // ---- phase a: wave-rows 0-63 (mq0), all 4 N-frags
    short8 af[4], bf4[4];
#pragma unroll
    for (int i = 0; i < 4; i++) af[i] = frag_ld(Ah, i * 16 + lr, lq);
#pragma unroll
    for (int jj = 0; jj < 4; jj++)
      bf4[jj] = frag_ld(Bh, bn0 + jj * 16 + lr, lq);
    if (pf) STG_A(sl2, k2);  // prefetch A half-tiles of tile j+2
    __builtin_amdgcn_s_barrier();
    __builtin_amdgcn_s_setprio(1);
#pragma unroll
    for (int i = 0; i < 4; i++)
#pragma unroll
      for (int jj = 0; jj < 4; jj++)
        acc[i][jj] = __builtin_amdgcn_mfma_f32_16x16x32_bf16(
            af[i], bf4[jj], acc[i][jj], 0, 0, 0);
    __builtin_amdgcn_s_setprio(0);
    __builtin_amdgcn_s_barrier();

    // ---- phase b: wave-rows 64-127 (mq1), reuse B frags (registers)
#pragma unroll
    for (int i = 0; i < 4; i++) af[i] = frag_ld(Ah, 64 + i * 16 + lr, lq);
    if (pf) {
      STG_B(sl2, k2);  // prefetch B half-tiles of tile j+2
      // counted wait: tile j+1 (oldest 4 loads) landed; tile j+2's 4 in flight
      asm volatile("s_waitcnt vmcnt(4)" ::: "memory");
    } else if (j == 30) {
      asm volatile("s_waitcnt vmcnt(0)" ::: "memory");  // drain tile 31
    }
    __builtin_amdgcn_s_barrier();
    __builtin_amdgcn_s_setprio(1);
#pragma unroll
    for (int i = 0; i < 4; i++)
#pragma unroll
      for (int jj = 0; jj < 4; jj++)
        acc[4 + i][jj] = __builtin_amdgcn_mfma_f32_16x16x32_bf16(
            af[i], bf4[jj], acc[4 + i][jj], 0, 0, 0);
    __builtin_amdgcn_s_setprio(0);
    __builtin_amdgcn_s_barrier();

    sl = (sl == 2) ? 0 : sl + 1;
    sl2 = (sl2 == 2) ? 0 : sl2 + 1;
  }
#undef STG_A
#undef STG_B

  // Epilogue. C/D layout: col = lane&15 (lr), row = lq*4 + rr.
  if (mode == 2) {
#pragma unroll
    for (int r = 0; r < 8; r++) {
      const int s0 = wm * 128 + r * 16 + lq * 4;  // s (within t), 4 contiguous
#pragma unroll
      for (int jj = 0; jj < 4; jj++) {
        const int cl = wn * 64 + jj * 16 + lr;
        const float bv = bias[cl];
        ushort4 h;
        h.x = f2bf(acc[r][jj][0] + bv);
        h.y = f2bf(acc[r][jj][1] + bv);
        h.z = f2bf(acc[r][jj][2] + bv);
        h.w = f2bf(acc[r][jj][3] + bv);
        *(ushort4*)&featsT[((size_t)mt * FF + nf0 + cl) * SS + s0] = h;
      }
    }
  } else {
    unsigned short* outp = (mode == 0) ? theta : phi;
#pragma unroll
    for (int r = 0; r < 8; r++) {
      const int row0 = m0 + wm * 128 + r * 16 + lq * 4;
#pragma unroll
      for (int jj = 0; jj < 4; jj++) {
        const int col = wn * 64 + jj * 16 + lr;
        const float bv = bias[col];
#pragma unroll
        for (int rr = 0; rr < 4; rr++)
          outp[(size_t)(row0 + rr) * AA + col] = f2bf(acc[r][jj][rr] + bv);
      }
    }
  }
}

// ---------------------------------------------------------------------------
// Fused projection GEMM, fp32-A FALLBACK (used only if workspace too small).
// ---------------------------------------------------------------------------
__global__ __launch_bounds__(256) void k_proj(
    const float* __restrict__ batch,
    const unsigned short* __restrict__ aT,
    const unsigned short* __restrict__ bT,
    const unsigned short* __restrict__ gT,
    const float* __restrict__ a_b, const float* __restrict__ b_b,
    const float* __restrict__ g_b,
    unsigned short* __restrict__ theta,
    unsigned short* __restrict__ phi,
    unsigned short* __restrict__ featsT) {
  const int K = FF;
  __shared__ unsigned short As[128 * 32];
  __shared__ unsigned short Bs[128 * 32];

  const int nt = blockIdx.x, mt = blockIdx.y;
  const int m0 = mt * 128;
  const unsigned short* Wt;
  const float* bias;
  int nloc0, mode;
  if (nt < 2)      { Wt = aT; bias = a_b; nloc0 = nt * 128;       mode = 0; }
  else if (nt < 4) { Wt = bT; bias = b_b; nloc0 = (nt - 2) * 128; mode = 1; }
  else             { Wt = gT; bias = g_b; nloc0 = (nt - 4) * 128; mode = 2; }

  const int tid = threadIdx.x;
  const int lane = tid & 63, wave = tid >> 6;
  const int wm = wave >> 1, wn = wave & 1;
  const int lr = lane & 15, lq = lane >> 4;

  floatx4 acc[4][4];
#pragma unroll
  for (int i = 0; i < 4; i++)
#pragma unroll
    for (int j = 0; j < 4; j++) acc[i][j] = (floatx4)0.0f;

  for (int k0 = 0; k0 < K; k0 += 32) {
    __syncthreads();
    {
      int sl = tid;
      gl_lds16(Wt + (size_t)(nloc0 + (sl >> 2)) * K + k0 + (sl & 3) * 8,
               &Bs[wave * 512]);
      sl = tid + 256;
      gl_lds16(Wt + (size_t)(nloc0 + (sl >> 2)) * K + k0 + (sl & 3) * 8,
               &Bs[2048 + wave * 512]);
    }
#pragma unroll
    for (int sgi = 0; sgi < 4; sgi++) {
      int g = sgi * 256 + tid;
      int row = g >> 3, c4 = g & 7;
      const floatx4 v =
          *(const floatx4*)(batch + (size_t)(m0 + row) * K + k0 + c4 * 4);
      ushort4 h;
      h.x = f2bf(v.x); h.y = f2bf(v.y); h.z = f2bf(v.z); h.w = f2bf(v.w);
      *(ushort4*)&As[row * 32 + c4 * 4] = h;
    }
    __syncthreads();

    short8 af[4], bfr[4];
#pragma unroll
    for (int i = 0; i < 4; i++)
      af[i] = *(const short8*)&As[(wm * 64 + i * 16 + lr) * 32 + lq * 8];
#pragma unroll
    for (int j = 0; j < 4; j++)
      bfr[j] = *(const short8*)&Bs[(wn * 64 + j * 16 + lr) * 32 + lq * 8];
#pragma unroll
    for (int i = 0; i < 4; i++)
#pragma unroll
      for (int j = 0; j < 4; j++)
        acc[i][j] = __builtin_amdgcn_mfma_f32_16x16x32_bf16(af[i], bfr[j],
                                                            acc[i][j], 0, 0, 0);
  }

#pragma unroll
  for (int i = 0; i < 4; i++) {
    const int row0 = wm * 64 + i * 16 + lq * 4;
#pragma unroll
    for (int j = 0; j < 4; j++) {
      const int col = wn * 64 + j * 16 + lr;
      const float bv = bias[nloc0 + col];
      if (mode == 2) {
        const int m = m0 + row0;
        const int t = m >> 8, s = m & 255;
        ushort4 h;
        h.x = f2bf(acc[i][j][0] + bv);
        h.y = f2bf(acc[i][j][1] + bv);
        h.z = f2bf(acc[i][j][2] + bv);
        h.w = f2bf(acc[i][j][3] + bv);
        *(ushort4*)&featsT[((size_t)t * FF + nloc0 + col) * SS + s] = h;
      } else {
        unsigned short* outp = (mode == 0) ? theta : phi;
#pragma unroll
        for (int rr = 0; rr < 4; rr++)
          outp[(size_t)(m0 + row0 + rr) * AA + nloc0 + col] =
              f2bf(acc[i][j][rr] + bv);
      }
    }
  }
}

// ---------------------------------------------------------------------------
// Fused attn+apply, one block per (t, m-half), XCD-chunked grid:
//   Phase 1: P = theta[t][m0:m0+128][:] @ phi[t]^T        (128x256, bf16 in LDS)
//   Phase 2: out[t][m0:m0+128][:] = P @ featsT[t]^T / 512 (2-phase dbuf,
//            ping-ponging between As and Bs; A-frags come from LDS P)
// P XOR-swizzled (byte ^= (row&7)<<4): phase-2 row-stride-512B ds_read_b128
// is a free 2-way conflict. LDS = 8 + 8 + 64 = 80 KB -> 2 blocks/CU.
// ---------------------------------------------------------------------------
__global__ __launch_bounds__(256) void k_fused(
    const unsigned short* __restrict__ theta,
    const unsigned short* __restrict__ phi,
    const unsigned short* __restrict__ featsT,
    float* __restrict__ out) {
  __shared__ unsigned short As[128 * 32];
  __shared__ unsigned short Bs[128 * 32];
  __shared__ unsigned short P[128 * 256];  // 64 KB, swizzled

  // Bijective swizzle: 512 = 8 xcd * 32 t * 2 mh; both mh of a t adjacent
  // on the same XCD -> featsT[t]/phi[t] shared in that XCD's L2.
  const int lin = blockIdx.x;
  const int xcd = lin & 7, idx = lin >> 3;  // idx in [0,64)
  const int t = xcd * 32 + (idx >> 1);
  const int mh = idx & 1;

  const int tid = threadIdx.x, lane = tid & 63, wave = tid >> 6;
  const int wm = wave >> 1, wn = wave & 1, lr = lane & 15, lq = lane >> 4;

  const unsigned short* Ath = theta + ((size_t)t * SS + mh * 128) * AA;
  const unsigned short* Bph = phi + (size_t)t * SS * AA;
  const unsigned short* Bft = featsT + (size_t)t * FF * SS;

  // ---- Phase 1: attn tile -> P (bf16, swizzled)
  for (int nb = 0; nb < 2; nb++) {
    floatx4 acc[4][4];
#pragma unroll
    for (int i = 0; i < 4; i++)
#pragma unroll
      for (int j = 0; j < 4; j++) acc[i][j] = (floatx4)0.0f;

    for (int k0 = 0; k0 < AA; k0 += 32) {
      __syncthreads();
      int sl = tid;
      gl_lds16(Ath + (size_t)(sl >> 2) * AA + k0 + (sl & 3) * 8,
               &As[wave * 512]);
      gl_lds16(Bph + (size_t)(nb * 128 + (sl >> 2)) * AA + k0 + (sl & 3) * 8,
               &Bs[wave * 512]);
      sl = tid + 256;
      gl_lds16(Ath + (size_t)(sl >> 2) * AA + k0 + (sl & 3) * 8,
               &As[2048 + wave * 512]);
      gl_lds16(Bph + (size_t)(nb * 128 + (sl >> 2)) * AA + k0 + (sl & 3) * 8,
               &Bs[2048 + wave * 512]);
      __syncthreads();

      short8 af[4], bfr[4];
#pragma unroll
      for (int i = 0; i < 4; i++)
        af[i] = *(const short8*)&As[(wm * 64 + i * 16 + lr) * 32 + lq * 8];
#pragma unroll
      for (int j = 0; j < 4; j++)
        bfr[j] = *(const short8*)&Bs[(wn * 64 + j * 16 + lr) * 32 + lq * 8];
#pragma unroll
      for (int i = 0; i < 4; i++)
#pragma unroll
        for (int j = 0; j < 4; j++)
          acc[i][j] = __builtin_amdgcn_mfma_f32_16x16x32_bf16(
              af[i], bfr[j], acc[i][j], 0, 0, 0);
    }

    // Write attn tile to P. C/D layout: col = lane&15, row = (lane>>4)*4+reg.
    // Per-wave quadrants are disjoint -> no race.
#pragma unroll
    for (int i = 0; i < 4; i++) {
#pragma unroll
      for (int j = 0; j < 4; j++) {
        const int colP = nb * 128 + wn * 64 + j * 16 + lr;
#pragma unroll
        for (int rr = 0; rr < 4; rr++) {
          const int rowP = wm * 64 + i * 16 + lq * 4 + rr;
          const unsigned off =
              ((unsigned)(rowP * 256 + colP) * 2u) ^ ((unsigned)(rowP & 7) << 4);
          *(unsigned short*)((char*)P + off) = f2bf(acc[i][j][rr]);
        }
      }
    }
  }
  __syncthreads();  // all phase-1 reads of As/Bs done; P writes ordered

  // ---- Phase 2: out = P @ featsT^T / 512, 2-phase dbuf (As <-> Bs)
#define STAGE_F2(dst_, nf_, k0_)                                              \
  do {                                                                        \
    int sl = tid;                                                             \
    gl_lds16(Bft + (size_t)((nf_) * 128 + (sl >> 2)) * SS + (k0_) +           \
                 (sl & 3) * 8,                                                \
             &(dst_)[wave * 512]);                                            \
    sl = tid + 256;                                                           \
    gl_lds16(Bft + (size_t)((nf_) * 128 + (sl >> 2)) * SS + (k0_) +           \
                 (sl & 3) * 8,                                                \
             &(dst_)[2048 + wave * 512]);                                     \
  } while (0)

  STAGE_F2(As, 0, 0);
  __syncthreads();  // buf(As) ready; also publishes P
  int cur = 0;      // 0 -> As holds current tile, 1 -> Bs

  const float inv = 1.0f / 512.0f;
  float* Ob = out + ((size_t)t * SS + mh * 128) * FF;
  for (int nf = 0; nf < 8; nf++) {
    floatx4 acc[4][4];
#pragma unroll
    for (int i = 0; i < 4; i++)
#pragma unroll
      for (int j = 0; j < 4; j++) acc[i][j] = (floatx4)0.0f;

    for (int k0 = 0; k0 < SS; k0 += 32) {
      int nnf = nf, nk = k0 + 32;
      if (nk == SS) { nnf++; nk = 0; }
      if (nnf < 8) {
        unsigned short* nxt = (cur == 0) ? Bs : As;
        STAGE_F2(nxt, nnf, nk);  // prefetch next tile
      }
      const unsigned short* curb = (cur == 0) ? As : Bs;

      short8 af[4], bfr[4];
#pragma unroll
      for (int i = 0; i < 4; i++) {
        const int rowP = wm * 64 + i * 16 + lr;
        const unsigned off = ((unsigned)(rowP * 256 + k0 + lq * 8) * 2u) ^
                             ((unsigned)(rowP & 7) << 4);
        af[i] = *(const short8*)((const char*)P + off);
      }
#pragma unroll
      for (int j = 0; j < 4; j++)
        bfr[j] = *(const short8*)&curb[(wn * 64 + j * 16 + lr) * 32 + lq * 8];
#pragma unroll
      for (int i = 0; i < 4; i++)
#pragma unroll
        for (int j = 0; j < 4; j++)
          acc[i][j] = __builtin_amdgcn_mfma_f32_16x16x32_bf16(
              af[i], bfr[j], acc[i][j], 0, 0, 0);
      __syncthreads();
      cur ^= 1;
    }
#undef STAGE_F2

#pragma unroll
    for (int i = 0; i < 4; i++) {
      const int row0 = wm * 64 + i * 16 + lq * 4;
#pragma unroll
      for (int j = 0; j < 4; j++) {
        const int col = nf * 128 + wn * 64 + j * 16 + lr;
#pragma unroll
        for (int rr = 0; rr < 4; rr++)
          Ob[(size_t)(row0 + rr) * FF + col] = acc[i][j][rr] * inv;
      }
    }
  }
}

// ---------------------------------------------------------------------------
extern "C" void kernel_launch(void* const* d_in, const int* in_sizes, int n_in,
                              void* d_out, int out_size, void* d_ws,
                              size_t ws_size, hipStream_t stream) {
  const float* batch = (const float*)d_in[0];
  const float* a_w   = (const float*)d_in[1];
  const float* a_b   = (const float*)d_in[2];
  const float* b_w   = (const float*)d_in[3];
  const float* b_b   = (const float*)d_in[4];
  const float* g_w   = (const float*)d_in[5];
  const float* g_b   = (const float*)d_in[6];
  float* out = (float*)d_out;

  // Workspace layout (bf16 elements).
  unsigned short* ws      = (unsigned short*)d_ws;
  unsigned short* aT      = ws;                                  // 256x1024
  unsigned short* bT      = aT + (size_t)AA * FF;                // 256x1024
  unsigned short* gT      = bT + (size_t)AA * FF;                // 1024x1024
  unsigned short* theta   = gT + (size_t)FF * FF;                // 65536x256
  unsigned short* phi     = theta + (size_t)TT * SS * AA;        // 65536x256
  unsigned short* featsT  = phi + (size_t)TT * SS * AA;          // [t][f][s]
  unsigned short* batch16 = featsT + (size_t)TT * FF * SS;       // 65536x1024

  const size_t need_b16 =
      ((size_t)2 * AA * FF + (size_t)FF * FF + (size_t)2 * TT * SS * AA +
       (size_t)TT * FF * SS + (size_t)TT * SS * FF) *
      sizeof(unsigned short);

  dim3 tb(32, 8);
  k_transpose_cvt<<<dim3(32, 8),  tb, 0, stream>>>(a_w, aT, FF, AA);
  k_transpose_cvt<<<dim3(32, 8),  tb, 0, stream>>>(b_w, bT, FF, AA);
  k_transpose_cvt<<<dim3(32, 32), tb, 0, stream>>>(g_w, gT, FF, FF);

  if (ws_size >= need_b16) {
    // One-shot batch fp32->bf16 (memory-bound), then pipelined 256^2 GEMM.
    k_cvt_bf16<<<2048, 256, 0, stream>>>(batch, batch16,
                                         (long)TT * SS * FF / 8);
    k_proj8<<<dim3(1536), 512, 0, stream>>>(batch16, aT, bT, gT, a_b, b_b,
                                            g_b, theta, phi, featsT);
  } else {
    // Fallback: fp32 in-kernel staging (previous verified path).
    k_proj<<<dim3(12, 512), 256, 0, stream>>>(batch, aT, bT, gT, a_b, b_b,
                                              g_b, theta, phi, featsT);
  }

  // Fused attn + apply: one block per (t, m-half); no attn round-trip.
  k_fused<<<dim3(512), 256, 0, stream>>>(theta, phi, featsT, out);
}

// Round 5
// 805.739 us; speedup vs baseline: 1.2039x; 1.0416x over previous
//
#include <hip/hip_runtime.h>
#include <stdint.h>

// Problem dims (fixed by the reference)
#define TT 256
#define SS 256
#define FF 1024
#define AA 256

typedef __attribute__((ext_vector_type(8))) short short8;
typedef __attribute__((ext_vector_type(8))) unsigned short ushort8v;
typedef __attribute__((ext_vector_type(4))) float floatx4;

// fp32 -> bf16 round-to-nearest-even
__device__ __forceinline__ unsigned short f2bf(float f) {
  unsigned int u = __float_as_uint(f);
  u += 0x7FFFu + ((u >> 16) & 1u);
  return (unsigned short)(u >> 16);
}

// async global->LDS, 16 B per lane; LDS dest = wave-uniform base + lane*16
__device__ __forceinline__ void gl_lds16(const unsigned short* g, unsigned short* l) {
  __builtin_amdgcn_global_load_lds(
      (__attribute__((address_space(1))) void*)(g),
      (__attribute__((address_space(3))) void*)(l), 16, 0, 0);
}

// swizzled LDS fragment read: logical (row, 16B-chunk lq) of a [R][32] bf16
// tile; phys byte = logical ^ ((bit9)<<5)  (st_16x32)
__device__ __forceinline__ short8 frag_ld(const unsigned short* base, int row,
                                          int lq) {
  unsigned l = (unsigned)(row * 64 + lq * 16);
  l ^= ((l >> 9) & 1u) << 5;
  return *(const short8*)((const char*)base + l);
}

// ---------------------------------------------------------------------------
// Whole-tensor fp32 -> bf16 convert (memory-bound pre-pass for batch).
// ---------------------------------------------------------------------------
__global__ __launch_bounds__(256) void k_cvt_bf16(const float* __restrict__ in,
                                                  unsigned short* __restrict__ out,
                                                  long n8) {
  long i = (long)blockIdx.x * 256 + threadIdx.x;
  const long stride = (long)gridDim.x * 256;
  for (; i < n8; i += stride) {
    const floatx4 v0 = *(const floatx4*)(in + i * 8);
    const floatx4 v1 = *(const floatx4*)(in + i * 8 + 4);
    ushort8v h;
    h[0] = f2bf(v0.x); h[1] = f2bf(v0.y); h[2] = f2bf(v0.z); h[3] = f2bf(v0.w);
    h[4] = f2bf(v1.x); h[5] = f2bf(v1.y); h[6] = f2bf(v1.z); h[7] = f2bf(v1.w);
    *(ushort8v*)(out + i * 8) = h;
  }
}

// ---------------------------------------------------------------------------
// Weight transpose + fp32->bf16:  WT[n][k] = bf16(W[k][n]).  W: K x N fp32.
// ---------------------------------------------------------------------------
__global__ void k_transpose_cvt(const float* __restrict__ W,
                                unsigned short* __restrict__ WT,
                                int K, int N) {
  __shared__ float tile[32][33];
  const int bk = blockIdx.x * 32, bn = blockIdx.y * 32;
  const int tx = threadIdx.x, ty = threadIdx.y;
  for (int i = ty; i < 32; i += 8)
    tile[i][tx] = W[(size_t)(bk + i) * N + bn + tx];
  __syncthreads();
  for (int i = ty; i < 32; i += 8)
    WT[(size_t)(bn + i) * K + bk + tx] = f2bf(tile[tx][i]);
}

// ---------------------------------------------------------------------------
// Projection GEMM, 256x256 tile, counted-vmcnt pipeline (T1+T2+T3+T4+T5).
// XCD map: hardware round-robins blockIdx across XCDs -> xcd = lin & 7.
//   n-tile 0 -> theta, 1 -> phi, 2..5 -> featsT[t][f][s]
// ---------------------------------------------------------------------------
__global__ __launch_bounds__(512, 2) void k_proj8(
    const unsigned short* __restrict__ batch16,
    const unsigned short* __restrict__ aT,
    const unsigned short* __restrict__ bT,
    const unsigned short* __restrict__ gT,
    const float* __restrict__ a_b, const float* __restrict__ b_b,
    const float* __restrict__ g_b,
    unsigned short* __restrict__ theta,
    unsigned short* __restrict__ phi,
    unsigned short* __restrict__ featsT) {
  const int K = FF;  // 1024
  __shared__ unsigned short Al[3][2][4096];  // [slot][m-half][128*32]
  __shared__ unsigned short Bl[3][2][4096];  // [slot][n-half][128*32]

  // XCD-chunked bijective grid: xcd = lin&7 (round-robin dispatch!);
  // idx in [0,192): nt fastest -> 6 same-A-panel blocks adjacent on one XCD.
  const int lin = blockIdx.x;
  const int xcd = lin & 7, idx = lin >> 3;
  const int nt = idx % 6;
  const int mt = xcd * 32 + idx / 6;
  const int m0 = mt * 256;

  const unsigned short* Wt;
  const float* bias;
  int mode, nf0 = 0;  // mode: 0 theta, 1 phi, 2 featsT
  if (nt == 0)      { Wt = aT; bias = a_b; mode = 0; }
  else if (nt == 1) { Wt = bT; bias = b_b; mode = 1; }
  else { nf0 = (nt - 2) * 256; Wt = gT + (size_t)nf0 * K; bias = g_b + nf0; mode = 2; }

  const int tid = threadIdx.x;
  const int lane = tid & 63, wave = tid >> 6;
  const int wm = wave >> 2, wn = wave & 3;   // 2 x 4 wave grid
  const int lr = lane & 15, lq = lane >> 4;
  const int bh = wn >> 1;                    // which B half this wave reads
  const int bn0 = (wn & 1) * 64;             // row base within B half

  // Staging source coords: LDS dest linear; SOURCE inverse-swizzled.
  const unsigned o = (unsigned)tid * 16u;
  const unsigned lo = o ^ (((o >> 9) & 1u) << 5);
  const int srow = (int)(lo >> 6);          // 0..127
  const int scol = (int)((lo & 63u) >> 1);  // 0..24 step 8
  const size_t aOff0 = (size_t)(m0 + srow) * K + scol;
  const size_t aOff1 = (size_t)(m0 + 128 + srow) * K + scol;
  const size_t bOff0 = (size_t)srow * K + scol;
  const size_t bOff1 = (size_t)(128 + srow) * K + scol;
  const int ldsb = wave * 512;  // wave-uniform dest base (elems)

#define STG_A(s_, k_)                                    \
  do {                                                   \
    gl_lds16(batch16 + aOff0 + (k_), &Al[s_][0][ldsb]);  \
    gl_lds16(batch16 + aOff1 + (k_), &Al[s_][1][ldsb]);  \
  } while (0)
#define STG_B(s_, k_)                              \
  do {                                             \
    gl_lds16(Wt + bOff0 + (k_), &Bl[s_][0][ldsb]); \
    gl_lds16(Wt + bOff1 + (k_), &Bl[s_][1][ldsb]); \
  } while (0)

  floatx4 acc[8][4];
#pragma unroll
  for (int i = 0; i < 8; i++)
#pragma unroll
    for (int j = 0; j < 4; j++) acc[i][j] = (floatx4)0.0f;

  // Prologue: stage K-tiles 0 and 1; wait for tile 0 only (tile 1 in flight).
  STG_A(0, 0);  STG_B(0, 0);
  STG_A(1, 32); STG_B(1, 32);
  asm volatile("s_waitcnt vmcnt(4)" ::: "memory");
  __builtin_amdgcn_s_barrier();

  int sl = 0, sl2 = 2;
  for (int j = 0; j < 32; ++j) {
    const unsigned short* Ah = Al[sl][wm];
    const unsigned short* Bh = Bl[sl][bh];
    const int k2 = j * 32 + 64;     // k0 of tile j+2
    const bool pf = (j < 30);

    // ---- phase a: wave-rows 0-63 (mq0), all 4 N-frags
    short8 af[4], bf4[4];
#pragma unroll
    for (int i = 0; i < 4; i++) af[i] = frag_ld(Ah, i * 16 + lr, lq);
#pragma unroll
    for (int jj = 0; jj < 4; jj++)
      bf4[jj] = frag_ld(Bh, bn0 + jj * 16 + lr, lq);
    if (pf) STG_A(sl2, k2);  // prefetch A half-tiles of tile j+2
    __builtin_amdgcn_s_barrier();
    __builtin_amdgcn_s_setprio(1);
#pragma unroll
    for (int i = 0; i < 4; i++)
#pragma unroll
      for (int jj = 0; jj < 4; jj++)
        acc[i][jj] = __builtin_amdgcn_mfma_f32_16x16x32_bf16(
            af[i], bf4[jj], acc[i][jj], 0, 0, 0);
    __builtin_amdgcn_s_setprio(0);
    __builtin_amdgcn_s_barrier();

    // ---- phase b: wave-rows 64-127 (mq1), reuse B frags (registers)
#pragma unroll
    for (int i = 0; i < 4; i++) af[i] = frag_ld(Ah, 64 + i * 16 + lr, lq);
    if (pf) {
      STG_B(sl2, k2);  // prefetch B half-tiles of tile j+2
      // counted wait: tile j+1 (oldest 4 loads) landed; tile j+2's 4 in flight
      asm volatile("s_waitcnt vmcnt(4)" ::: "memory");
    } else if (j == 30) {
      asm volatile("s_waitcnt vmcnt(0)" ::: "memory");  // drain tile 31
    }
    __builtin_amdgcn_s_barrier();
    __builtin_amdgcn_s_setprio(1);
#pragma unroll
    for (int i = 0; i < 4; i++)
#pragma unroll
      for (int jj = 0; jj < 4; jj++)
        acc[4 + i][jj] = __builtin_amdgcn_mfma_f32_16x16x32_bf16(
            af[i], bf4[jj], acc[4 + i][jj], 0, 0, 0);
    __builtin_amdgcn_s_setprio(0);
    __builtin_amdgcn_s_barrier();

    sl = (sl == 2) ? 0 : sl + 1;
    sl2 = (sl2 == 2) ? 0 : sl2 + 1;
  }
#undef STG_A
#undef STG_B

  // Epilogue. C/D layout: col = lane&15 (lr), row = lq*4 + rr.
  if (mode == 2) {
#pragma unroll
    for (int r = 0; r < 8; r++) {
      const int s0 = wm * 128 + r * 16 + lq * 4;  // s (within t), 4 contiguous
#pragma unroll
      for (int jj = 0; jj < 4; jj++) {
        const int cl = wn * 64 + jj * 16 + lr;
        const float bv = bias[cl];
        ushort4 h;
        h.x = f2bf(acc[r][jj][0] + bv);
        h.y = f2bf(acc[r][jj][1] + bv);
        h.z = f2bf(acc[r][jj][2] + bv);
        h.w = f2bf(acc[r][jj][3] + bv);
        *(ushort4*)&featsT[((size_t)mt * FF + nf0 + cl) * SS + s0] = h;
      }
    }
  } else {
    unsigned short* outp = (mode == 0) ? theta : phi;
#pragma unroll
    for (int r = 0; r < 8; r++) {
      const int row0 = m0 + wm * 128 + r * 16 + lq * 4;
#pragma unroll
      for (int jj = 0; jj < 4; jj++) {
        const int col = wn * 64 + jj * 16 + lr;
        const float bv = bias[col];
#pragma unroll
        for (int rr = 0; rr < 4; rr++)
          outp[(size_t)(row0 + rr) * AA + col] = f2bf(acc[r][jj][rr] + bv);
      }
    }
  }
}

// ---------------------------------------------------------------------------
// Fused projection GEMM, fp32-A FALLBACK (used only if workspace too small).
// ---------------------------------------------------------------------------
__global__ __launch_bounds__(256) void k_proj(
    const float* __restrict__ batch,
    const unsigned short* __restrict__ aT,
    const unsigned short* __restrict__ bT,
    const unsigned short* __restrict__ gT,
    const float* __restrict__ a_b, const float* __restrict__ b_b,
    const float* __restrict__ g_b,
    unsigned short* __restrict__ theta,
    unsigned short* __restrict__ phi,
    unsigned short* __restrict__ featsT) {
  const int K = FF;
  __shared__ unsigned short As[128 * 32];
  __shared__ unsigned short Bs[128 * 32];

  const int nt = blockIdx.x, mt = blockIdx.y;
  const int m0 = mt * 128;
  const unsigned short* Wt;
  const float* bias;
  int nloc0, mode;
  if (nt < 2)      { Wt = aT; bias = a_b; nloc0 = nt * 128;       mode = 0; }
  else if (nt < 4) { Wt = bT; bias = b_b; nloc0 = (nt - 2) * 128; mode = 1; }
  else             { Wt = gT; bias = g_b; nloc0 = (nt - 4) * 128; mode = 2; }

  const int tid = threadIdx.x;
  const int lane = tid & 63, wave = tid >> 6;
  const int wm = wave >> 1, wn = wave & 1;
  const int lr = lane & 15, lq = lane >> 4;

  floatx4 acc[4][4];
#pragma unroll
  for (int i = 0; i < 4; i++)
#pragma unroll
    for (int j = 0; j < 4; j++) acc[i][j] = (floatx4)0.0f;

  for (int k0 = 0; k0 < K; k0 += 32) {
    __syncthreads();
    {
      int sl = tid;
      gl_lds16(Wt + (size_t)(nloc0 + (sl >> 2)) * K + k0 + (sl & 3) * 8,
               &Bs[wave * 512]);
      sl = tid + 256;
      gl_lds16(Wt + (size_t)(nloc0 + (sl >> 2)) * K + k0 + (sl & 3) * 8,
               &Bs[2048 + wave * 512]);
    }
#pragma unroll
    for (int sgi = 0; sgi < 4; sgi++) {
      int g = sgi * 256 + tid;
      int row = g >> 3, c4 = g & 7;
      const floatx4 v =
          *(const floatx4*)(batch + (size_t)(m0 + row) * K + k0 + c4 * 4);
      ushort4 h;
      h.x = f2bf(v.x); h.y = f2bf(v.y); h.z = f2bf(v.z); h.w = f2bf(v.w);
      *(ushort4*)&As[row * 32 + c4 * 4] = h;
    }
    __syncthreads();

    short8 af[4], bfr[4];
#pragma unroll
    for (int i = 0; i < 4; i++)
      af[i] = *(const short8*)&As[(wm * 64 + i * 16 + lr) * 32 + lq * 8];
#pragma unroll
    for (int j = 0; j < 4; j++)
      bfr[j] = *(const short8*)&Bs[(wn * 64 + j * 16 + lr) * 32 + lq * 8];
#pragma unroll
    for (int i = 0; i < 4; i++)
#pragma unroll
      for (int j = 0; j < 4; j++)
        acc[i][j] = __builtin_amdgcn_mfma_f32_16x16x32_bf16(af[i], bfr[j],
                                                            acc[i][j], 0, 0, 0);
  }

#pragma unroll
  for (int i = 0; i < 4; i++) {
    const int row0 = wm * 64 + i * 16 + lq * 4;
#pragma unroll
    for (int j = 0; j < 4; j++) {
      const int col = wn * 64 + j * 16 + lr;
      const float bv = bias[nloc0 + col];
      if (mode == 2) {
        const int m = m0 + row0;
        const int t = m >> 8, s = m & 255;
        ushort4 h;
        h.x = f2bf(acc[i][j][0] + bv);
        h.y = f2bf(acc[i][j][1] + bv);
        h.z = f2bf(acc[i][j][2] + bv);
        h.w = f2bf(acc[i][j][3] + bv);
        *(ushort4*)&featsT[((size_t)t * FF + nloc0 + col) * SS + s] = h;
      } else {
        unsigned short* outp = (mode == 0) ? theta : phi;
#pragma unroll
        for (int rr = 0; rr < 4; rr++)
          outp[(size_t)(m0 + row0 + rr) * AA + nloc0 + col] =
              f2bf(acc[i][j][rr] + bv);
      }
    }
  }
}

// ---------------------------------------------------------------------------
// Fused attn+apply v2: one block per (t, m-half), 512 threads, 8 waves (2x4),
// counted-vmcnt pipelines throughout (proj8 recipe):
//   Phase 1: P = theta[t][mh*128..][:] @ phi[t]^T  (128x256 bf16 -> LDS P)
//            2-slot dbuf {A 8K | B 16K}, vmcnt(3) counted, raw barriers.
//   Phase 2: out = P @ featsT[t]^T / 512           (128x1024 fp32)
//            3-slot ring of [256f][32r] 16K tiles, vmcnt(2) counted,
//            ONE barrier/iter; f-chunks of 256 reuse acc[4][4].
// P XOR-swizzled (byte ^= (row&7)<<4); ring/dbuf st_16x32-swizzled via
// inverse-swizzled global source (both-sides rule).
// LDS = 48 KB ring + 64 KB P = 112 KB -> 1 block/CU; 512 blocks = 2 rounds.
// ---------------------------------------------------------------------------
__global__ __launch_bounds__(512) void k_fused2(
    const unsigned short* __restrict__ theta,
    const unsigned short* __restrict__ phi,
    const unsigned short* __restrict__ featsT,
    float* __restrict__ out) {
  __shared__ unsigned short ring[24576];   // 48 KB
  __shared__ unsigned short P[128 * 256];  // 64 KB, swizzled

  // XCD map (round-robin dispatch): pair (t,0),(t,1) adjacent on one XCD.
  const int lin = blockIdx.x;
  const int xcd = lin & 7, idx = lin >> 3;  // idx in [0,64)
  const int t = xcd * 32 + (idx >> 1);
  const int mh = idx & 1;

  const int tid = threadIdx.x, lane = tid & 63, wave = tid >> 6;
  const int wm = wave >> 2, wn = wave & 3;  // 2 x 4 wave grid
  const int lr = lane & 15, lq = lane >> 4;

  const unsigned short* Ath = theta + ((size_t)t * SS + mh * 128) * AA;
  const unsigned short* Bph = phi + (size_t)t * SS * AA;
  const unsigned short* Bft = featsT + (size_t)t * FF * SS;

  // Inverse-swizzled staging source coords (per 8 KB round, o = tid*16).
  const unsigned o = (unsigned)tid * 16u;
  const unsigned lo = o ^ (((o >> 9) & 1u) << 5);
  const int srow = (int)(lo >> 6);          // 0..127
  const int scol = (int)((lo & 63u) >> 1);  // 0..24 step 8
  const int ldsb = wave * 512;              // elems

  // ======== Phase 1: attn tile -> P ========
  // slot s: A tile at ring[s*12288], B tile at ring[s*12288 + 4096]
#define STG_P1(s_, k_)                                                       \
  do {                                                                       \
    gl_lds16(Ath + (size_t)srow * AA + (k_) + scol, &ring[(s_)*12288 + ldsb]); \
    gl_lds16(Bph + (size_t)srow * AA + (k_) + scol,                          \
             &ring[(s_)*12288 + 4096 + ldsb]);                               \
    gl_lds16(Bph + (size_t)(128 + srow) * AA + (k_) + scol,                  \
             &ring[(s_)*12288 + 8192 + ldsb]);                               \
  } while (0)

  floatx4 acc[4][4];
#pragma unroll
  for (int i = 0; i < 4; i++)
#pragma unroll
    for (int j = 0; j < 4; j++) acc[i][j] = (floatx4)0.0f;

  STG_P1(0, 0);
  STG_P1(1, 32);
  for (int k = 0; k < 8; ++k) {
    if (k < 7)
      asm volatile("s_waitcnt vmcnt(3)" ::: "memory");  // tile k landed
    else
      asm volatile("s_waitcnt vmcnt(0)" ::: "memory");
    __builtin_amdgcn_s_barrier();

    const unsigned short* Abase = &ring[(k & 1) * 12288];
    const unsigned short* Bbase = Abase + 4096;
    short8 af[4], bf4[4];
#pragma unroll
    for (int i = 0; i < 4; i++)
      af[i] = frag_ld(Abase, wm * 64 + i * 16 + lr, lq);
#pragma unroll
    for (int j = 0; j < 4; j++)
      bf4[j] = frag_ld(Bbase, wn * 64 + j * 16 + lr, lq);
    asm volatile("s_waitcnt lgkmcnt(0)" ::: "memory");  // reads done ...
    __builtin_amdgcn_s_barrier();                        // ... for ALL waves
    if (k + 2 < 8) STG_P1(k & 1, (k + 2) * 32);          // overwrite cur slot

    __builtin_amdgcn_s_setprio(1);
#pragma unroll
    for (int i = 0; i < 4; i++)
#pragma unroll
      for (int j = 0; j < 4; j++)
        acc[i][j] = __builtin_amdgcn_mfma_f32_16x16x32_bf16(af[i], bf4[j],
                                                            acc[i][j], 0, 0, 0);
    __builtin_amdgcn_s_setprio(0);
  }
#undef STG_P1

  // Write attn tile to P (bf16, swizzled). col = lr-frag n, row = lq*4+rr.
#pragma unroll
  for (int i = 0; i < 4; i++) {
#pragma unroll
    for (int j = 0; j < 4; j++) {
      const int colP = wn * 64 + j * 16 + lr;
#pragma unroll
      for (int rr = 0; rr < 4; rr++) {
        const int rowP = wm * 64 + i * 16 + lq * 4 + rr;
        const unsigned off =
            ((unsigned)(rowP * 256 + colP) * 2u) ^ ((unsigned)(rowP & 7) << 4);
        *(unsigned short*)((char*)P + off) = f2bf(acc[i][j][rr]);
      }
    }
  }
  __syncthreads();  // P published; all phase-1 ring reads complete

  // ======== Phase 2: out = P @ featsT^T / 512 ========
  // 32 tiles T = c*8 + k (c = f-chunk of 256, k = r-tile of 32).
  // slot = T % 3, 16 KB each at ring[slot*8192].
#define STG_P2(slot_, T_)                                                    \
  do {                                                                       \
    const int c_ = (T_) >> 3, k_ = ((T_)&7) * 32;                            \
    gl_lds16(Bft + (size_t)(c_ * 256 + srow) * SS + k_ + scol,               \
             &ring[(slot_)*8192 + ldsb]);                                    \
    gl_lds16(Bft + (size_t)(c_ * 256 + 128 + srow) * SS + k_ + scol,         \
             &ring[(slot_)*8192 + 4096 + ldsb]);                             \
  } while (0)

  STG_P2(0, 0);
  STG_P2(1, 1);

  const float inv = 1.0f / 512.0f;
  float* Ob = out + ((size_t)t * SS + mh * 128) * FF;

#pragma unroll
  for (int i = 0; i < 4; i++)
#pragma unroll
    for (int j = 0; j < 4; j++) acc[i][j] = (floatx4)0.0f;

  int slot = 0, slot2 = 2;
  for (int T = 0; T < 32; ++T) {
    if (T < 31)
      asm volatile("s_waitcnt vmcnt(2)" ::: "memory");  // tile T landed
    else
      asm volatile("s_waitcnt vmcnt(0)" ::: "memory");
    __builtin_amdgcn_s_barrier();

    const int k0 = (T & 7) * 32;
    const unsigned short* Bbase = &ring[slot * 8192];
    short8 af[4], bf4[4];
#pragma unroll
    for (int i = 0; i < 4; i++) {
      const int rowP = wm * 64 + i * 16 + lr;
      const unsigned off = ((unsigned)(rowP * 256 + k0 + lq * 8) * 2u) ^
                           ((unsigned)(rowP & 7) << 4);
      af[i] = *(const short8*)((const char*)P + off);
    }
#pragma unroll
    for (int j = 0; j < 4; j++)
      bf4[j] = frag_ld(Bbase, wn * 64 + j * 16 + lr, lq);
    if (T + 2 < 32) STG_P2(slot2, T + 2);  // targets slot of T-1 (reads done)

    __builtin_amdgcn_s_setprio(1);
#pragma unroll
    for (int i = 0; i < 4; i++)
#pragma unroll
      for (int j = 0; j < 4; j++)
        acc[i][j] = __builtin_amdgcn_mfma_f32_16x16x32_bf16(af[i], bf4[j],
                                                            acc[i][j], 0, 0, 0);
    __builtin_amdgcn_s_setprio(0);

    if ((T & 7) == 7) {  // f-chunk complete: write out, reset acc
      const int c = T >> 3;
#pragma unroll
      for (int i = 0; i < 4; i++) {
        const int row0 = wm * 64 + i * 16 + lq * 4;
#pragma unroll
        for (int j = 0; j < 4; j++) {
          const int col = c * 256 + wn * 64 + j * 16 + lr;
#pragma unroll
          for (int rr = 0; rr < 4; rr++)
            Ob[(size_t)(row0 + rr) * FF + col] = acc[i][j][rr] * inv;
          acc[i][j] = (floatx4)0.0f;
        }
      }
    }
    slot = (slot == 2) ? 0 : slot + 1;
    slot2 = (slot2 == 2) ? 0 : slot2 + 1;
  }
#undef STG_P2
}

// ---------------------------------------------------------------------------
extern "C" void kernel_launch(void* const* d_in, const int* in_sizes, int n_in,
                              void* d_out, int out_size, void* d_ws,
                              size_t ws_size, hipStream_t stream) {
  const float* batch = (const float*)d_in[0];
  const float* a_w   = (const float*)d_in[1];
  const float* a_b   = (const float*)d_in[2];
  const float* b_w   = (const float*)d_in[3];
  const float* b_b   = (const float*)d_in[4];
  const float* g_w   = (const float*)d_in[5];
  const float* g_b   = (const float*)d_in[6];
  float* out = (float*)d_out;

  // Workspace layout (bf16 elements).
  unsigned short* ws      = (unsigned short*)d_ws;
  unsigned short* aT      = ws;                                  // 256x1024
  unsigned short* bT      = aT + (size_t)AA * FF;                // 256x1024
  unsigned short* gT      = bT + (size_t)AA * FF;                // 1024x1024
  unsigned short* theta   = gT + (size_t)FF * FF;                // 65536x256
  unsigned short* phi     = theta + (size_t)TT * SS * AA;        // 65536x256
  unsigned short* featsT  = phi + (size_t)TT * SS * AA;          // [t][f][s]
  unsigned short* batch16 = featsT + (size_t)TT * FF * SS;       // 65536x1024

  const size_t need_b16 =
      ((size_t)2 * AA * FF + (size_t)FF * FF + (size_t)2 * TT * SS * AA +
       (size_t)TT * FF * SS + (size_t)TT * SS * FF) *
      sizeof(unsigned short);

  dim3 tb(32, 8);
  k_transpose_cvt<<<dim3(32, 8),  tb, 0, stream>>>(a_w, aT, FF, AA);
  k_transpose_cvt<<<dim3(32, 8),  tb, 0, stream>>>(b_w, bT, FF, AA);
  k_transpose_cvt<<<dim3(32, 32), tb, 0, stream>>>(g_w, gT, FF, FF);

  if (ws_size >= need_b16) {
    // One-shot batch fp32->bf16 (memory-bound), then pipelined 256^2 GEMM.
    k_cvt_bf16<<<2048, 256, 0, stream>>>(batch, batch16,
                                         (long)TT * SS * FF / 8);
    k_proj8<<<dim3(1536), 512, 0, stream>>>(batch16, aT, bT, gT, a_b, b_b,
                                            g_b, theta, phi, featsT);
  } else {
    // Fallback: fp32 in-kernel staging (previous verified path).
    k_proj<<<dim3(12, 512), 256, 0, stream>>>(batch, aT, bT, gT, a_b, b_b,
                                              g_b, theta, phi, featsT);
  }

  // Fused attn + apply v2: counted-vmcnt pipelines, no attn round-trip.
  k_fused2<<<dim3(512), 512, 0, stream>>>(theta, phi, featsT, out);
}

// Round 6
// 788.412 us; speedup vs baseline: 1.2304x; 1.0220x over previous
//
#include <hip/hip_runtime.h>
#include <stdint.h>

// Problem dims (fixed by the reference)
#define TT 256
#define SS 256
#define FF 1024
#define AA 256

typedef __attribute__((ext_vector_type(8))) short short8;
typedef __attribute__((ext_vector_type(8))) unsigned short ushort8v;
typedef __attribute__((ext_vector_type(4))) float floatx4;

// fp32 -> bf16 round-to-nearest-even
__device__ __forceinline__ unsigned short f2bf(float f) {
  unsigned int u = __float_as_uint(f);
  u += 0x7FFFu + ((u >> 16) & 1u);
  return (unsigned short)(u >> 16);
}

// async global->LDS, 16 B per lane; LDS dest = wave-uniform base + lane*16
__device__ __forceinline__ void gl_lds16(const unsigned short* g, unsigned short* l) {
  __builtin_amdgcn_global_load_lds(
      (__attribute__((address_space(1))) void*)(g),
      (__attribute__((address_space(3))) void*)(l), 16, 0, 0);
}

// swizzled LDS fragment read: logical (row, 16B-chunk lq) of a [R][32] bf16
// tile; phys byte = logical ^ ((bit9)<<5)  (st_16x32)
__device__ __forceinline__ short8 frag_ld(const unsigned short* base, int row,
                                          int lq) {
  unsigned l = (unsigned)(row * 64 + lq * 16);
  l ^= ((l >> 9) & 1u) << 5;
  return *(const short8*)((const char*)base + l);
}

// ---------------------------------------------------------------------------
// Whole-tensor fp32 -> bf16 convert (memory-bound pre-pass for batch).
// ---------------------------------------------------------------------------
__global__ __launch_bounds__(256) void k_cvt_bf16(const float* __restrict__ in,
                                                  unsigned short* __restrict__ out,
                                                  long n8) {
  long i = (long)blockIdx.x * 256 + threadIdx.x;
  const long stride = (long)gridDim.x * 256;
  for (; i < n8; i += stride) {
    const floatx4 v0 = *(const floatx4*)(in + i * 8);
    const floatx4 v1 = *(const floatx4*)(in + i * 8 + 4);
    ushort8v h;
    h[0] = f2bf(v0.x); h[1] = f2bf(v0.y); h[2] = f2bf(v0.z); h[3] = f2bf(v0.w);
    h[4] = f2bf(v1.x); h[5] = f2bf(v1.y); h[6] = f2bf(v1.z); h[7] = f2bf(v1.w);
    *(ushort8v*)(out + i * 8) = h;
  }
}

// ---------------------------------------------------------------------------
// Weight transpose + fp32->bf16:  WT[n][k] = bf16(W[k][n]).  W: K x N fp32.
// ---------------------------------------------------------------------------
__global__ void k_transpose_cvt(const float* __restrict__ W,
                                unsigned short* __restrict__ WT,
                                int K, int N) {
  __shared__ float tile[32][33];
  const int bk = blockIdx.x * 32, bn = blockIdx.y * 32;
  const int tx = threadIdx.x, ty = threadIdx.y;
  for (int i = ty; i < 32; i += 8)
    tile[i][tx] = W[(size_t)(bk + i) * N + bn + tx];
  __syncthreads();
  for (int i = ty; i < 32; i += 8)
    WT[(size_t)(bn + i) * K + bk + tx] = f2bf(tile[tx][i]);
}

// ---------------------------------------------------------------------------
// Projection GEMM, 256x256 tile, fully software-pipelined single-barrier
// K-loop:
//   regs hold frags(j); each iter: ds_read frags(j+1) || STG tile j+3 ||
//   32 MFMA on frags(j); then lgkmcnt(0), vmcnt(4) (counted, BEFORE the
//   barrier so the cross-wave "tile j+2 landed" guarantee holds), s_barrier.
//   ONE barrier + ONE vmcnt per K-tile (was 4 barriers).
// 3-slot LDS ring (96 KB), st_16x32 swizzle (inverse-swizzled source +
// swizzled reads), XCD-chunked grid, setprio around MFMA cluster.
//   n-tile 0 -> theta, 1 -> phi, 2..5 -> featsT[t][f][s]
// ---------------------------------------------------------------------------
__global__ __launch_bounds__(512, 2) void k_proj8(
    const unsigned short* __restrict__ batch16,
    const unsigned short* __restrict__ aT,
    const unsigned short* __restrict__ bT,
    const unsigned short* __restrict__ gT,
    const float* __restrict__ a_b, const float* __restrict__ b_b,
    const float* __restrict__ g_b,
    unsigned short* __restrict__ theta,
    unsigned short* __restrict__ phi,
    unsigned short* __restrict__ featsT) {
  const int K = FF;  // 1024
  __shared__ unsigned short Al[3][2][4096];  // [slot][m-half][128*32]
  __shared__ unsigned short Bl[3][2][4096];  // [slot][n-half][128*32]

  // XCD-chunked bijective grid: xcd = lin&7 (round-robin dispatch);
  // nt fastest -> 6 same-A-panel blocks adjacent on one XCD's L2.
  const int lin = blockIdx.x;
  const int xcd = lin & 7, idx = lin >> 3;
  const int nt = idx % 6;
  const int mt = xcd * 32 + idx / 6;
  const int m0 = mt * 256;

  const unsigned short* Wt;
  const float* bias;
  int mode, nf0 = 0;  // mode: 0 theta, 1 phi, 2 featsT
  if (nt == 0)      { Wt = aT; bias = a_b; mode = 0; }
  else if (nt == 1) { Wt = bT; bias = b_b; mode = 1; }
  else { nf0 = (nt - 2) * 256; Wt = gT + (size_t)nf0 * K; bias = g_b + nf0; mode = 2; }

  const int tid = threadIdx.x;
  const int lane = tid & 63, wave = tid >> 6;
  const int wm = wave >> 2, wn = wave & 3;   // 2 x 4 wave grid
  const int lr = lane & 15, lq = lane >> 4;
  const int bh = wn >> 1;                    // which B half this wave reads
  const int bn0 = (wn & 1) * 64;             // row base within B half

  // Staging source coords: LDS dest linear; SOURCE inverse-swizzled.
  const unsigned o = (unsigned)tid * 16u;
  const unsigned lo = o ^ (((o >> 9) & 1u) << 5);
  const int srow = (int)(lo >> 6);          // 0..127
  const int scol = (int)((lo & 63u) >> 1);  // 0..24 step 8
  const unsigned aoff = (unsigned)(srow * K + scol);  // 32-bit lane offset
  const int ldsb = wave * 512;              // wave-uniform dest base (elems)

  const unsigned short* pA0 = batch16 + (size_t)m0 * K;
  const unsigned short* pA1 = pA0 + (size_t)128 * K;
  const unsigned short* pB0 = Wt;
  const unsigned short* pB1 = Wt + (size_t)128 * K;

  floatx4 acc[8][4];
#pragma unroll
  for (int i = 0; i < 8; i++)
#pragma unroll
    for (int j = 0; j < 4; j++) acc[i][j] = (floatx4)0.0f;

  short8 fA0[8], fB0[4], fA1[8], fB1[4];

  // ---- Prologue: stage t0(slot0), t1(slot1); read frags(t0); stage t2.
  gl_lds16(pA0 + aoff + 0, &Al[0][0][ldsb]);
  gl_lds16(pA1 + aoff + 0, &Al[0][1][ldsb]);
  gl_lds16(pB0 + aoff - aoff + ((unsigned)(srow * K + scol)), &Bl[0][0][ldsb]);
  gl_lds16(pB1 + aoff - aoff + ((unsigned)(srow * K + scol)), &Bl[0][1][ldsb]);
  gl_lds16(pA0 + aoff + 32, &Al[1][0][ldsb]);
  gl_lds16(pA1 + aoff + 32, &Al[1][1][ldsb]);
  gl_lds16(pB0 + aoff + 32, &Bl[1][0][ldsb]);
  gl_lds16(pB1 + aoff + 32, &Bl[1][1][ldsb]);
  asm volatile("s_waitcnt vmcnt(4)" ::: "memory");  // t0 landed
  __builtin_amdgcn_s_barrier();
#pragma unroll
  for (int i = 0; i < 8; i++)
    fA0[i] = frag_ld(Al[0][wm], ((i >> 2) * 64) + (i & 3) * 16 + lr, lq);
#pragma unroll
  for (int i = 0; i < 4; i++)
    fB0[i] = frag_ld(Bl[0][bh], bn0 + i * 16 + lr, lq);
  gl_lds16(pA0 + aoff + 64, &Al[2][0][ldsb]);
  gl_lds16(pA1 + aoff + 64, &Al[2][1][ldsb]);
  gl_lds16(pB0 + aoff + 64, &Bl[2][0][ldsb]);
  gl_lds16(pB1 + aoff + 64, &Bl[2][1][ldsb]);
  asm volatile("s_waitcnt lgkmcnt(0)" ::: "memory");
  __builtin_amdgcn_sched_barrier(0);
  asm volatile("s_waitcnt vmcnt(4)" ::: "memory");  // t1 landed (t2 in flight)
  __builtin_amdgcn_s_barrier();

  int slR = 1, slW = 0, kst = 96;  // kst = k0 of tile j+3

  // Body for tile j: CUR frags -> MFMA; read NXT=frags(j+1); optional STG j+3.
#define PBODY(CA, CB, NA, NB, DOSTG, VM)                                     \
  do {                                                                       \
    const unsigned short* Ah_ = Al[slR][wm];                                 \
    const unsigned short* Bh_ = Bl[slR][bh];                                 \
    _Pragma("unroll") for (int i_ = 0; i_ < 8; i_++)                         \
        NA[i_] = frag_ld(Ah_, ((i_ >> 2) * 64) + (i_ & 3) * 16 + lr, lq);    \
    _Pragma("unroll") for (int i_ = 0; i_ < 4; i_++)                         \
        NB[i_] = frag_ld(Bh_, bn0 + i_ * 16 + lr, lq);                       \
    if (DOSTG) {                                                             \
      gl_lds16(pA0 + aoff + kst, &Al[slW][0][ldsb]);                         \
      gl_lds16(pA1 + aoff + kst, &Al[slW][1][ldsb]);                         \
      gl_lds16(pB0 + aoff + kst, &Bl[slW][0][ldsb]);                         \
      gl_lds16(pB1 + aoff + kst, &Bl[slW][1][ldsb]);                         \
    }                                                                        \
    __builtin_amdgcn_s_setprio(1);                                           \
    _Pragma("unroll") for (int i_ = 0; i_ < 8; i_++)                         \
      _Pragma("unroll") for (int j_ = 0; j_ < 4; j_++)                       \
          acc[i_][j_] = __builtin_amdgcn_mfma_f32_16x16x32_bf16(             \
              CA[i_], CB[j_], acc[i_][j_], 0, 0, 0);                         \
    __builtin_amdgcn_s_setprio(0);                                           \
    asm volatile("s_waitcnt lgkmcnt(0)" ::: "memory");                       \
    __builtin_amdgcn_sched_barrier(0);                                       \
    asm volatile("s_waitcnt vmcnt(" VM ")" ::: "memory");                    \
    __builtin_amdgcn_s_barrier();                                            \
    slW = slR; slR = (slR == 2) ? 0 : slR + 1; kst += 32;                    \
  } while (0)

  for (int jt = 0; jt < 14; ++jt) {  // tiles j = 0..27
    PBODY(fA0, fB0, fA1, fB1, 1, "4");
    PBODY(fA1, fB1, fA0, fB0, 1, "4");
  }
  PBODY(fA0, fB0, fA1, fB1, 1, "4");  // j=28: STG t31
  PBODY(fA1, fB1, fA0, fB0, 0, "0");  // j=29: drain t31
  PBODY(fA0, fB0, fA1, fB1, 0, "0");  // j=30: reads frags(31)
  // j=31: MFMA only
  __builtin_amdgcn_s_setprio(1);
#pragma unroll
  for (int i = 0; i < 8; i++)
#pragma unroll
    for (int j = 0; j < 4; j++)
      acc[i][j] = __builtin_amdgcn_mfma_f32_16x16x32_bf16(fA1[i], fB1[j],
                                                          acc[i][j], 0, 0, 0);
  __builtin_amdgcn_s_setprio(0);
#undef PBODY

  // Epilogue. C/D layout: col = lane&15 (lr), row = lq*4 + rr.
  if (mode == 2) {
#pragma unroll
    for (int r = 0; r < 8; r++) {
      const int s0 = wm * 128 + r * 16 + lq * 4;  // s (within t), 4 contiguous
#pragma unroll
      for (int jj = 0; jj < 4; jj++) {
        const int cl = wn * 64 + jj * 16 + lr;
        const float bv = bias[cl];
        ushort4 h;
        h.x = f2bf(acc[r][jj][0] + bv);
        h.y = f2bf(acc[r][jj][1] + bv);
        h.z = f2bf(acc[r][jj][2] + bv);
        h.w = f2bf(acc[r][jj][3] + bv);
        *(ushort4*)&featsT[((size_t)mt * FF + nf0 + cl) * SS + s0] = h;
      }
    }
  } else {
    unsigned short* outp = (mode == 0) ? theta : phi;
#pragma unroll
    for (int r = 0; r < 8; r++) {
      const int row0 = m0 + wm * 128 + r * 16 + lq * 4;
#pragma unroll
      for (int jj = 0; jj < 4; jj++) {
        const int col = wn * 64 + jj * 16 + lr;
        const float bv = bias[col];
#pragma unroll
        for (int rr = 0; rr < 4; rr++)
          outp[(size_t)(row0 + rr) * AA + col] = f2bf(acc[r][jj][rr] + bv);
      }
    }
  }
}

// ---------------------------------------------------------------------------
// Fused projection GEMM, fp32-A FALLBACK (used only if workspace too small).
// ---------------------------------------------------------------------------
__global__ __launch_bounds__(256) void k_proj(
    const float* __restrict__ batch,
    const unsigned short* __restrict__ aT,
    const unsigned short* __restrict__ bT,
    const unsigned short* __restrict__ gT,
    const float* __restrict__ a_b, const float* __restrict__ b_b,
    const float* __restrict__ g_b,
    unsigned short* __restrict__ theta,
    unsigned short* __restrict__ phi,
    unsigned short* __restrict__ featsT) {
  const int K = FF;
  __shared__ unsigned short As[128 * 32];
  __shared__ unsigned short Bs[128 * 32];

  const int nt = blockIdx.x, mt = blockIdx.y;
  const int m0 = mt * 128;
  const unsigned short* Wt;
  const float* bias;
  int nloc0, mode;
  if (nt < 2)      { Wt = aT; bias = a_b; nloc0 = nt * 128;       mode = 0; }
  else if (nt < 4) { Wt = bT; bias = b_b; nloc0 = (nt - 2) * 128; mode = 1; }
  else             { Wt = gT; bias = g_b; nloc0 = (nt - 4) * 128; mode = 2; }

  const int tid = threadIdx.x;
  const int lane = tid & 63, wave = tid >> 6;
  const int wm = wave >> 1, wn = wave & 1;
  const int lr = lane & 15, lq = lane >> 4;

  floatx4 acc[4][4];
#pragma unroll
  for (int i = 0; i < 4; i++)
#pragma unroll
    for (int j = 0; j < 4; j++) acc[i][j] = (floatx4)0.0f;

  for (int k0 = 0; k0 < K; k0 += 32) {
    __syncthreads();
    {
      int sl = tid;
      gl_lds16(Wt + (size_t)(nloc0 + (sl >> 2)) * K + k0 + (sl & 3) * 8,
               &Bs[wave * 512]);
      sl = tid + 256;
      gl_lds16(Wt + (size_t)(nloc0 + (sl >> 2)) * K + k0 + (sl & 3) * 8,
               &Bs[2048 + wave * 512]);
    }
#pragma unroll
    for (int sgi = 0; sgi < 4; sgi++) {
      int g = sgi * 256 + tid;
      int row = g >> 3, c4 = g & 7;
      const floatx4 v =
          *(const floatx4*)(batch + (size_t)(m0 + row) * K + k0 + c4 * 4);
      ushort4 h;
      h.x = f2bf(v.x); h.y = f2bf(v.y); h.z = f2bf(v.z); h.w = f2bf(v.w);
      *(ushort4*)&As[row * 32 + c4 * 4] = h;
    }
    __syncthreads();

    short8 af[4], bfr[4];
#pragma unroll
    for (int i = 0; i < 4; i++)
      af[i] = *(const short8*)&As[(wm * 64 + i * 16 + lr) * 32 + lq * 8];
#pragma unroll
    for (int j = 0; j < 4; j++)
      bfr[j] = *(const short8*)&Bs[(wn * 64 + j * 16 + lr) * 32 + lq * 8];
#pragma unroll
    for (int i = 0; i < 4; i++)
#pragma unroll
      for (int j = 0; j < 4; j++)
        acc[i][j] = __builtin_amdgcn_mfma_f32_16x16x32_bf16(af[i], bfr[j],
                                                            acc[i][j], 0, 0, 0);
  }

#pragma unroll
  for (int i = 0; i < 4; i++) {
    const int row0 = wm * 64 + i * 16 + lq * 4;
#pragma unroll
    for (int j = 0; j < 4; j++) {
      const int col = wn * 64 + j * 16 + lr;
      const float bv = bias[nloc0 + col];
      if (mode == 2) {
        const int m = m0 + row0;
        const int t = m >> 8, s = m & 255;
        ushort4 h;
        h.x = f2bf(acc[i][j][0] + bv);
        h.y = f2bf(acc[i][j][1] + bv);
        h.z = f2bf(acc[i][j][2] + bv);
        h.w = f2bf(acc[i][j][3] + bv);
        *(ushort4*)&featsT[((size_t)t * FF + nloc0 + col) * SS + s] = h;
      } else {
        unsigned short* outp = (mode == 0) ? theta : phi;
#pragma unroll
        for (int rr = 0; rr < 4; rr++)
          outp[(size_t)(m0 + row0 + rr) * AA + nloc0 + col] =
              f2bf(acc[i][j][rr] + bv);
      }
    }
  }
}

// ---------------------------------------------------------------------------
// Fused attn+apply v2 (unchanged from round 5 for attribution):
//   Phase 1: P = theta[t][mh*128..][:] @ phi[t]^T  (128x256 bf16 -> LDS P)
//   Phase 2: out = P @ featsT[t]^T / 512           (3-slot ring, vmcnt(2))
// ---------------------------------------------------------------------------
__global__ __launch_bounds__(512) void k_fused2(
    const unsigned short* __restrict__ theta,
    const unsigned short* __restrict__ phi,
    const unsigned short* __restrict__ featsT,
    float* __restrict__ out) {
  __shared__ unsigned short ring[24576];   // 48 KB
  __shared__ unsigned short P[128 * 256];  // 64 KB, swizzled

  const int lin = blockIdx.x;
  const int xcd = lin & 7, idx = lin >> 3;  // idx in [0,64)
  const int t = xcd * 32 + (idx >> 1);
  const int mh = idx & 1;

  const int tid = threadIdx.x, lane = tid & 63, wave = tid >> 6;
  const int wm = wave >> 2, wn = wave & 3;  // 2 x 4 wave grid
  const int lr = lane & 15, lq = lane >> 4;

  const unsigned short* Ath = theta + ((size_t)t * SS + mh * 128) * AA;
  const unsigned short* Bph = phi + (size_t)t * SS * AA;
  const unsigned short* Bft = featsT + (size_t)t * FF * SS;

  const unsigned o = (unsigned)tid * 16u;
  const unsigned lo = o ^ (((o >> 9) & 1u) << 5);
  const int srow = (int)(lo >> 6);          // 0..127
  const int scol = (int)((lo & 63u) >> 1);  // 0..24 step 8
  const int ldsb = wave * 512;              // elems

  // ======== Phase 1: attn tile -> P ========
#define STG_P1(s_, k_)                                                       \
  do {                                                                       \
    gl_lds16(Ath + (size_t)srow * AA + (k_) + scol, &ring[(s_)*12288 + ldsb]); \
    gl_lds16(Bph + (size_t)srow * AA + (k_) + scol,                          \
             &ring[(s_)*12288 + 4096 + ldsb]);                               \
    gl_lds16(Bph + (size_t)(128 + srow) * AA + (k_) + scol,                  \
             &ring[(s_)*12288 + 8192 + ldsb]);                               \
  } while (0)

  floatx4 acc[4][4];
#pragma unroll
  for (int i = 0; i < 4; i++)
#pragma unroll
    for (int j = 0; j < 4; j++) acc[i][j] = (floatx4)0.0f;

  STG_P1(0, 0);
  STG_P1(1, 32);
  for (int k = 0; k < 8; ++k) {
    if (k < 7)
      asm volatile("s_waitcnt vmcnt(3)" ::: "memory");  // tile k landed
    else
      asm volatile("s_waitcnt vmcnt(0)" ::: "memory");
    __builtin_amdgcn_s_barrier();

    const unsigned short* Abase = &ring[(k & 1) * 12288];
    const unsigned short* Bbase = Abase + 4096;
    short8 af[4], bf4[4];
#pragma unroll
    for (int i = 0; i < 4; i++)
      af[i] = frag_ld(Abase, wm * 64 + i * 16 + lr, lq);
#pragma unroll
    for (int j = 0; j < 4; j++)
      bf4[j] = frag_ld(Bbase, wn * 64 + j * 16 + lr, lq);
    asm volatile("s_waitcnt lgkmcnt(0)" ::: "memory");
    __builtin_amdgcn_s_barrier();
    if (k + 2 < 8) STG_P1(k & 1, (k + 2) * 32);

    __builtin_amdgcn_s_setprio(1);
#pragma unroll
    for (int i = 0; i < 4; i++)
#pragma unroll
      for (int j = 0; j < 4; j++)
        acc[i][j] = __builtin_amdgcn_mfma_f32_16x16x32_bf16(af[i], bf4[j],
                                                            acc[i][j], 0, 0, 0);
    __builtin_amdgcn_s_setprio(0);
  }
#undef STG_P1

#pragma unroll
  for (int i = 0; i < 4; i++) {
#pragma unroll
    for (int j = 0; j < 4; j++) {
      const int colP = wn * 64 + j * 16 + lr;
#pragma unroll
      for (int rr = 0; rr < 4; rr++) {
        const int rowP = wm * 64 + i * 16 + lq * 4 + rr;
        const unsigned off =
            ((unsigned)(rowP * 256 + colP) * 2u) ^ ((unsigned)(rowP & 7) << 4);
        *(unsigned short*)((char*)P + off) = f2bf(acc[i][j][rr]);
      }
    }
  }
  __syncthreads();  // P published; all phase-1 ring reads complete

  // ======== Phase 2: out = P @ featsT^T / 512 ========
#define STG_P2(slot_, T_)                                                    \
  do {                                                                       \
    const int c_ = (T_) >> 3, k_ = ((T_)&7) * 32;                            \
    gl_lds16(Bft + (size_t)(c_ * 256 + srow) * SS + k_ + scol,               \
             &ring[(slot_)*8192 + ldsb]);                                    \
    gl_lds16(Bft + (size_t)(c_ * 256 + 128 + srow) * SS + k_ + scol,         \
             &ring[(slot_)*8192 + 4096 + ldsb]);                             \
  } while (0)

  STG_P2(0, 0);
  STG_P2(1, 1);

  const float inv = 1.0f / 512.0f;
  float* Ob = out + ((size_t)t * SS + mh * 128) * FF;

#pragma unroll
  for (int i = 0; i < 4; i++)
#pragma unroll
    for (int j = 0; j < 4; j++) acc[i][j] = (floatx4)0.0f;

  int slot = 0, slot2 = 2;
  for (int T = 0; T < 32; ++T) {
    if (T < 31)
      asm volatile("s_waitcnt vmcnt(2)" ::: "memory");  // tile T landed
    else
      asm volatile("s_waitcnt vmcnt(0)" ::: "memory");
    __builtin_amdgcn_s_barrier();

    const int k0 = (T & 7) * 32;
    const unsigned short* Bbase = &ring[slot * 8192];
    short8 af[4], bf4[4];
#pragma unroll
    for (int i = 0; i < 4; i++) {
      const int rowP = wm * 64 + i * 16 + lr;
      const unsigned off = ((unsigned)(rowP * 256 + k0 + lq * 8) * 2u) ^
                           ((unsigned)(rowP & 7) << 4);
      af[i] = *(const short8*)((const char*)P + off);
    }
#pragma unroll
    for (int j = 0; j < 4; j++)
      bf4[j] = frag_ld(Bbase, wn * 64 + j * 16 + lr, lq);
    if (T + 2 < 32) STG_P2(slot2, T + 2);

    __builtin_amdgcn_s_setprio(1);
#pragma unroll
    for (int i = 0; i < 4; i++)
#pragma unroll
      for (int j = 0; j < 4; j++)
        acc[i][j] = __builtin_amdgcn_mfma_f32_16x16x32_bf16(af[i], bf4[j],
                                                            acc[i][j], 0, 0, 0);
    __builtin_amdgcn_s_setprio(0);

    if ((T & 7) == 7) {  // f-chunk complete: write out, reset acc
      const int c = T >> 3;
#pragma unroll
      for (int i = 0; i < 4; i++) {
        const int row0 = wm * 64 + i * 16 + lq * 4;
#pragma unroll
        for (int j = 0; j < 4; j++) {
          const int col = c * 256 + wn * 64 + j * 16 + lr;
#pragma unroll
          for (int rr = 0; rr < 4; rr++)
            Ob[(size_t)(row0 + rr) * FF + col] = acc[i][j][rr] * inv;
          acc[i][j] = (floatx4)0.0f;
        }
      }
    }
    slot = (slot == 2) ? 0 : slot + 1;
    slot2 = (slot2 == 2) ? 0 : slot2 + 1;
  }
#undef STG_P2
}

// ---------------------------------------------------------------------------
extern "C" void kernel_launch(void* const* d_in, const int* in_sizes, int n_in,
                              void* d_out, int out_size, void* d_ws,
                              size_t ws_size, hipStream_t stream) {
  const float* batch = (const float*)d_in[0];
  const float* a_w   = (const float*)d_in[1];
  const float* a_b   = (const float*)d_in[2];
  const float* b_w   = (const float*)d_in[3];
  const float* b_b   = (const float*)d_in[4];
  const float* g_w   = (const float*)d_in[5];
  const float* g_b   = (const float*)d_in[6];
  float* out = (float*)d_out;

  // Workspace layout (bf16 elements).
  unsigned short* ws      = (unsigned short*)d_ws;
  unsigned short* aT      = ws;                                  // 256x1024
  unsigned short* bT      = aT + (size_t)AA * FF;                // 256x1024
  unsigned short* gT      = bT + (size_t)AA * FF;                // 1024x1024
  unsigned short* theta   = gT + (size_t)FF * FF;                // 65536x256
  unsigned short* phi     = theta + (size_t)TT * SS * AA;        // 65536x256
  unsigned short* featsT  = phi + (size_t)TT * SS * AA;          // [t][f][s]
  unsigned short* batch16 = featsT + (size_t)TT * FF * SS;       // 65536x1024

  const size_t need_b16 =
      ((size_t)2 * AA * FF + (size_t)FF * FF + (size_t)2 * TT * SS * AA +
       (size_t)TT * FF * SS + (size_t)TT * SS * FF) *
      sizeof(unsigned short);

  dim3 tb(32, 8);
  k_transpose_cvt<<<dim3(32, 8),  tb, 0, stream>>>(a_w, aT, FF, AA);
  k_transpose_cvt<<<dim3(32, 8),  tb, 0, stream>>>(b_w, bT, FF, AA);
  k_transpose_cvt<<<dim3(32, 32), tb, 0, stream>>>(g_w, gT, FF, FF);

  if (ws_size >= need_b16) {
    // One-shot batch fp32->bf16 (memory-bound), then pipelined 256^2 GEMM.
    k_cvt_bf16<<<2048, 256, 0, stream>>>(batch, batch16,
                                         (long)TT * SS * FF / 8);
    k_proj8<<<dim3(1536), 512, 0, stream>>>(batch16, aT, bT, gT, a_b, b_b,
                                            g_b, theta, phi, featsT);
  } else {
    // Fallback: fp32 in-kernel staging (previous verified path).
    k_proj<<<dim3(12, 512), 256, 0, stream>>>(batch, aT, bT, gT, a_b, b_b,
                                              g_b, theta, phi, featsT);
  }

  // Fused attn + apply v2: counted-vmcnt pipelines, no attn round-trip.
  k_fused2<<<dim3(512), 512, 0, stream>>>(theta, phi, featsT, out);
}